// Round 13
// baseline (6276.687 us; speedup 1.0000x reference)
//
#include <hip/hip_runtime.h>

#define DIMM 1024
#define NHEADS 8
#define DH 128
#define NSLOTS 128
#define CHUNK 256
#define NCHUNK 16
#define NB 2
#define SEQ 4096
#define NROWS (NB * SEQ)
#define NVOCAB 32000
#define GAMMA64 0.9
#define SCALE64 0.08838834764831845
#define TAU 1e-6f
#define MAXFLAG 65536

typedef unsigned short u16;
typedef __attribute__((ext_vector_type(4))) float f32x4;
typedef __attribute__((ext_vector_type(8))) short s16x8;

struct alignas(8) u16x4 { u16 x, y, z, w; };

__device__ __forceinline__ u16 f2bf(float f) {
  union { float f; unsigned u; } v; v.f = f;
  return (u16)((v.u + 0x7FFFu + ((v.u >> 16) & 1u)) >> 16);
}
__device__ __forceinline__ float bf2f(u16 u) {
  union { unsigned u; float f; } v; v.u = ((unsigned)u) << 16; return v.f;
}
// exact 3-way bf16 split of an f32 (h+m+l == x exactly)
__device__ __forceinline__ void split3s(float x, u16& h, u16& m, u16& l) {
  h = f2bf(x); float r = x - bf2f(h);
  m = f2bf(r); float r2 = r - bf2f(m);
  l = f2bf(r2);
}

__device__ __forceinline__ void gld16(void* lds, const void* g) {
  __builtin_amdgcn_global_load_lds(
      (const __attribute__((address_space(1))) unsigned*)g,
      (__attribute__((address_space(3))) unsigned*)lds, 16, 0, 0);
}
__device__ __forceinline__ f32x4 mfma16(s16x8 a, s16x8 b, f32x4 c) {
  return __builtin_amdgcn_mfma_f32_16x16x32_bf16(a, b, c, 0, 0, 0);
}

// ---------------- embedding gather -> f64 ----------------
__global__ __launch_bounds__(256) void embed64_kernel(
    const int* __restrict__ tok, const float* __restrict__ emb,
    double* __restrict__ hid) {
  const int row = blockIdx.x;
  const int t = tok[row];
  const float4 v = ((const float4*)(emb + (size_t)t * DIMM))[threadIdx.x];
  double* o = hid + (size_t)row * DIMM + threadIdx.x * 4;
  o[0] = (double)v.x; o[1] = (double)v.y; o[2] = (double)v.z; o[3] = (double)v.w;
}

// ------- f64 two-pass layernorm; MODE0: f64 xn + split3; MODE1: bf16 -------
template <int MODE>
__global__ __launch_bounds__(256) void ln64_kernel(
    const double* __restrict__ x, const float* __restrict__ g,
    const float* __restrict__ bb, double* __restrict__ o64,
    u16* __restrict__ oh, u16* __restrict__ om, u16* __restrict__ ol) {
  const int row = blockIdx.x, tid = threadIdx.x;
  const double* xr = x + (size_t)row * DIMM + tid * 4;
  const double v0 = xr[0], v1 = xr[1], v2 = xr[2], v3 = xr[3];
  __shared__ double red[4];
  double s1 = v0 + v1 + v2 + v3;
#pragma unroll
  for (int off = 32; off >= 1; off >>= 1) s1 += __shfl_xor(s1, off);
  if ((tid & 63) == 0) red[tid >> 6] = s1;
  __syncthreads();
  const double mu = (red[0] + red[1] + red[2] + red[3]) * (1.0 / DIMM);
  __syncthreads();
  const double d0 = v0 - mu, d1 = v1 - mu, d2 = v2 - mu, d3 = v3 - mu;
  double s2 = d0 * d0 + d1 * d1 + d2 * d2 + d3 * d3;
#pragma unroll
  for (int off = 32; off >= 1; off >>= 1) s2 += __shfl_xor(s2, off);
  if ((tid & 63) == 0) red[tid >> 6] = s2;
  __syncthreads();
  const double var = (red[0] + red[1] + red[2] + red[3]) * (1.0 / DIMM);
  const double rs = 1.0 / sqrt(var + 1e-5);
  const float4 g4 = ((const float4*)g)[tid];
  const float4 b4 = ((const float4*)bb)[tid];
  const double y0 = d0 * rs * (double)g4.x + (double)b4.x;
  const double y1 = d1 * rs * (double)g4.y + (double)b4.y;
  const double y2 = d2 * rs * (double)g4.z + (double)b4.z;
  const double y3 = d3 * rs * (double)g4.w + (double)b4.w;
  if (MODE == 0) {
    double* o = o64 + (size_t)row * DIMM + tid * 4;
    o[0] = y0; o[1] = y1; o[2] = y2; o[3] = y3;
    u16x4 rh, rm, rl;
    split3s((float)y0, rh.x, rm.x, rl.x);
    split3s((float)y1, rh.y, rm.y, rl.y);
    split3s((float)y2, rh.z, rm.z, rl.z);
    split3s((float)y3, rh.w, rm.w, rl.w);
    ((u16x4*)(oh + (size_t)row * DIMM))[tid] = rh;
    ((u16x4*)(om + (size_t)row * DIMM))[tid] = rm;
    ((u16x4*)(ol + (size_t)row * DIMM))[tid] = rl;
  } else {
    u16x4 r;
    r.x = f2bf((float)y0); r.y = f2bf((float)y1);
    r.z = f2bf((float)y2); r.w = f2bf((float)y3);
    ((u16x4*)(oh + (size_t)row * DIMM))[tid] = r;
  }
}

// ---------------- W[K][N] f32 -> WT[N][K] split3 bf16 ----------------
__global__ void transconv3_kernel(const float* __restrict__ W,
                                  u16* __restrict__ WTh, u16* __restrict__ WTm,
                                  u16* __restrict__ WTl, int K, int N) {
  __shared__ float tile[32][33];
  const int n0 = blockIdx.x * 32, k0 = blockIdx.y * 32;
  const int tx = threadIdx.x, ty = threadIdx.y;
#pragma unroll
  for (int i = 0; i < 4; i++)
    tile[ty + 8 * i][tx] = W[(size_t)(k0 + ty + 8 * i) * N + n0 + tx];
  __syncthreads();
#pragma unroll
  for (int i = 0; i < 4; i++) {
    u16 h, m, l;
    split3s(tile[tx][ty + 8 * i], h, m, l);
    const size_t o = (size_t)(n0 + ty + 8 * i) * K + k0 + tx;
    WTh[o] = h; WTm[o] = m; WTl[o] = l;
  }
}

// ---------------- f32 -> split3 bf16 elementwise ----------------
__global__ __launch_bounds__(256) void cvt3_32_kernel(
    const float* __restrict__ in, u16* __restrict__ oh, u16* __restrict__ om,
    u16* __restrict__ ol) {
  const size_t i = (size_t)blockIdx.x * 256 + threadIdx.x;
  const float4 v = ((const float4*)in)[i];
  u16x4 rh, rm, rl;
  split3s(v.x, rh.x, rm.x, rl.x); split3s(v.y, rh.y, rm.y, rl.y);
  split3s(v.z, rh.z, rm.z, rl.z); split3s(v.w, rh.w, rm.w, rl.w);
  ((u16x4*)oh)[i] = rh; ((u16x4*)om)[i] = rm; ((u16x4*)ol)[i] = rl;
}

// ---------------- combined slot-score weights: W2 (f64 exact) --------------
__global__ __launch_bounds__(256) void w2_kernel(const float* __restrict__ W,
                                                 const float* __restrict__ sk,
                                                 double* __restrict__ W2) {
  __shared__ float sksh[128];
  const int r = blockIdx.x, h = r >> 7;
  const int tid = threadIdx.x;
  if (tid < 128) sksh[tid] = sk[(size_t)r * DH + tid];
  __syncthreads();
  for (int d = tid; d < DIMM; d += 256) {
    const float* wrow = W + (size_t)d * DIMM + h * DH;
    double acc = 0.0;
#pragma unroll 8
    for (int j = 0; j < 128; j++) acc += (double)wrow[j] * (double)sksh[j];
    W2[(size_t)r * DIMM + d] = acc;
  }
}

// ------- split3 f32-faithful GEMM -> TC out: C = A @ BT^T (+res) ----------
template <bool RES, typename TC>
__global__ __launch_bounds__(256) void gemm3d_kernel(
    const u16* __restrict__ Ah, const u16* __restrict__ Am,
    const u16* __restrict__ Al, const u16* __restrict__ Bh,
    const u16* __restrict__ Bm, const u16* __restrict__ Bl,
    TC* __restrict__ C, const TC* __restrict__ Cres, int M, int N, int K) {
  __shared__ u16 lds[6 * 128 * 32];
  const int tid = threadIdx.x;
  const int bn = blockIdx.x, bm = blockIdx.y;
  const int wid = tid >> 6, lane = tid & 63;
  const int wr = (wid >> 1) * 64, wc = (wid & 1) * 64;
  f32x4 acc[4][4] = {};
  const int row0 = tid >> 2;
  const int colb = (tid & 3) << 4;
  const u16* Gs[6] = {Ah, Am, Al, Bh, Bm, Bl};
  const char* g0[6];
  const char* g1[6];
  char* lb[6];
#pragma unroll
  for (int i = 0; i < 6; i++) {
    const int rbase = (i < 3 ? bm : bn) * 128;
    g0[i] = (const char*)Gs[i] + ((size_t)(rbase + row0) * K) * 2 + colb;
    g1[i] = (const char*)Gs[i] + ((size_t)(rbase + row0 + 64) * K) * 2 + colb;
    lb[i] = (char*)lds + i * 8192 + (tid & 192) * 16;
  }
  const int fo = (lane & 15) * 64 + (lane >> 4) * 16;
  const char* paH = (const char*)lds + 0 + wr * 64 + fo;
  const char* paM = paH + 8192;
  const char* paL = paH + 16384;
  const char* pbH = (const char*)lds + 24576 + wc * 64 + fo;
  const char* pbM = pbH + 8192;
  const char* pbL = pbH + 16384;

  for (int k0 = 0; k0 < K; k0 += 32) {
    const size_t kb = (size_t)k0 * 2;
#pragma unroll
    for (int i = 0; i < 6; i++) {
      gld16(lb[i], g0[i] + kb);
      gld16(lb[i] + 4096, g1[i] + kb);
    }
    __syncthreads();
    s16x8 bh[4], bm_[4], bl[4];
#pragma unroll
    for (int n = 0; n < 4; n++) {
      bh[n] = *(const s16x8*)(pbH + n * 1024);
      bm_[n] = *(const s16x8*)(pbM + n * 1024);
      bl[n] = *(const s16x8*)(pbL + n * 1024);
    }
#pragma unroll
    for (int m = 0; m < 4; m++) {
      const s16x8 ah = *(const s16x8*)(paH + m * 1024);
      const s16x8 am = *(const s16x8*)(paM + m * 1024);
      const s16x8 al = *(const s16x8*)(paL + m * 1024);
#pragma unroll
      for (int n = 0; n < 4; n++) {
        f32x4 t = acc[m][n];
        t = mfma16(al, bh[n], t);
        t = mfma16(ah, bl[n], t);
        t = mfma16(am, bm_[n], t);
        t = mfma16(am, bh[n], t);
        t = mfma16(ah, bm_[n], t);
        t = mfma16(ah, bh[n], t);
        acc[m][n] = t;
      }
    }
    __syncthreads();
  }
#pragma unroll
  for (int m = 0; m < 4; m++)
#pragma unroll
    for (int n = 0; n < 4; n++)
#pragma unroll
      for (int j = 0; j < 4; j++) {
        const int r = bm * 128 + wr + m * 16 + (lane >> 4) * 4 + j;
        const int c = bn * 128 + wc + n * 16 + (lane & 15);
        TC v = (TC)acc[m][n][j];
        if (RES) v += Cres[(size_t)r * N + c];
        C[(size_t)r * N + c] = v;
      }
}

// ------- slot scores via split3 MFMA: S[which][rid][slot] (f32) ------------
__global__ __launch_bounds__(256) void score3_kernel(
    const u16* __restrict__ Qh, const u16* __restrict__ Qm,
    const u16* __restrict__ Ql, const u16* __restrict__ Kh3,
    const u16* __restrict__ Km3, const u16* __restrict__ Kl3,
    const u16* __restrict__ skh, const u16* __restrict__ skm,
    const u16* __restrict__ skl, float* __restrict__ S) {
  __shared__ u16 lds[6 * 128 * 32];
  const int tid = threadIdx.x;
  const int bm = blockIdx.x;
  const int y = blockIdx.y;
  const int which = y >> 4, b = (y >> 3) & 1, h = y & 7;
  const u16* Ah = which ? Kh3 : Qh;
  const u16* Am = which ? Km3 : Qm;
  const u16* Al = which ? Kl3 : Ql;
  const int wid = tid >> 6, lane = tid & 63;
  const int wr = (wid >> 1) * 64, wc = (wid & 1) * 64;
  f32x4 acc[4][4] = {};
  const int row0 = tid >> 2;
  const int colb = (tid & 3) << 4;
  const size_t arow = (size_t)(b * SEQ + bm * 128);
  const u16* Gs[6] = {Ah, Am, Al, skh, skm, skl};
  const char* g0[6];
  const char* g1[6];
  char* lb[6];
#pragma unroll
  for (int i = 0; i < 6; i++) {
    if (i < 3) {
      g0[i] = (const char*)Gs[i] + (arow + row0) * 2048 + h * 256 + colb;
      g1[i] = (const char*)Gs[i] + (arow + row0 + 64) * 2048 + h * 256 + colb;
    } else {
      g0[i] = (const char*)Gs[i] + ((size_t)h * 128 + row0) * 256 + colb;
      g1[i] = (const char*)Gs[i] + ((size_t)h * 128 + row0 + 64) * 256 + colb;
    }
    lb[i] = (char*)lds + i * 8192 + (tid & 192) * 16;
  }
  const int fo = (lane & 15) * 64 + (lane >> 4) * 16;
  const char* paH = (const char*)lds + 0 + wr * 64 + fo;
  const char* paM = paH + 8192;
  const char* paL = paH + 16384;
  const char* pbH = (const char*)lds + 24576 + wc * 64 + fo;
  const char* pbM = pbH + 8192;
  const char* pbL = pbH + 16384;

  for (int k0 = 0; k0 < DH; k0 += 32) {
    const size_t kb = (size_t)k0 * 2;
#pragma unroll
    for (int i = 0; i < 6; i++) {
      gld16(lb[i], g0[i] + kb);
      gld16(lb[i] + 4096, g1[i] + kb);
    }
    __syncthreads();
    s16x8 bh[4], bm_[4], bl[4];
#pragma unroll
    for (int n = 0; n < 4; n++) {
      bh[n] = *(const s16x8*)(pbH + n * 1024);
      bm_[n] = *(const s16x8*)(pbM + n * 1024);
      bl[n] = *(const s16x8*)(pbL + n * 1024);
    }
#pragma unroll
    for (int m = 0; m < 4; m++) {
      const s16x8 ah = *(const s16x8*)(paH + m * 1024);
      const s16x8 am = *(const s16x8*)(paM + m * 1024);
      const s16x8 al = *(const s16x8*)(paL + m * 1024);
#pragma unroll
      for (int n = 0; n < 4; n++) {
        f32x4 t = acc[m][n];
        t = mfma16(al, bh[n], t);
        t = mfma16(ah, bl[n], t);
        t = mfma16(am, bm_[n], t);
        t = mfma16(am, bh[n], t);
        t = mfma16(ah, bm_[n], t);
        t = mfma16(ah, bh[n], t);
        acc[m][n] = t;
      }
    }
    __syncthreads();
  }
  const size_t sbase =
      (size_t)which * 65536 + (size_t)(b * 8 + h) * 4096 + (size_t)bm * 128;
#pragma unroll
  for (int m = 0; m < 4; m++)
#pragma unroll
    for (int n = 0; n < 4; n++)
#pragma unroll
      for (int j = 0; j < 4; j++) {
        const int r = wr + m * 16 + (lane >> 4) * 4 + j;
        const int c = wc + n * 16 + (lane & 15);
        S[(sbase + r) * NSLOTS + c] = acc[m][n][j];
      }
}

// -------- top-16 selection on precomputed f32 scores + flagging ------------
__global__ __launch_bounds__(256) void select_kernel(
    const float* __restrict__ S, int* __restrict__ riQ, int* __restrict__ riK,
    double* __restrict__ rwQ, double* __restrict__ rwK,
    int* __restrict__ fcnts, int* __restrict__ flq, int* __restrict__ flk) {
  const int which = blockIdx.y;
  int* oidx = which ? riK : riQ;
  double* ow = which ? rwK : rwQ;
  int* fcnt = fcnts + which;
  int* flist = which ? flk : flq;
  const int wid = threadIdx.x >> 6, lane = threadIdx.x & 63;
  const int rid = blockIdx.x * 4 + wid;
  const float2 sv =
      *(const float2*)(S + ((size_t)which * 65536 + rid) * NSLOTS + lane * 2);
  const float sc = (float)SCALE64;
  float v0 = sv.x * sc, v1 = sv.y * sc;
  const int i0 = lane * 2, i1 = lane * 2 + 1;
  float selv = -1e30f; int seli = 0;
  for (int it = 0; it < 17; it++) {
    float m; int mi;
    if (v1 > v0) { m = v1; mi = i1; } else { m = v0; mi = i0; }
#pragma unroll
    for (int off = 1; off < 64; off <<= 1) {
      const float om = __shfl_xor(m, off);
      const int oi = __shfl_xor(mi, off);
      if (om > m || (om == m && oi < mi)) { m = om; mi = oi; }
    }
    if (lane == it) { selv = m; seli = mi; }
    if (mi == i0) v0 = -1e30f;
    if (mi == i1) v1 = -1e30f;
  }
  const float mx = __shfl(selv, 0);
  const float v15 = __shfl(selv, 15);
  const float v16 = __shfl(selv, 16);
  if (lane == 0 && (v15 - v16) < TAU) {
    const int p = atomicAdd(fcnt, 1);
    if (p < MAXFLAG) flist[p] = rid;
  }
  const float e = (lane < 16) ? expf(selv - mx) : 0.0f;
  double ss = (double)e;
  ss += __shfl_xor(ss, 1); ss += __shfl_xor(ss, 2);
  ss += __shfl_xor(ss, 4); ss += __shfl_xor(ss, 8);
  if (lane < 16) {
    ow[(size_t)rid * 16 + lane] = (double)e / ss;
    oidx[(size_t)rid * 16 + lane] = seli;
  }
}

// ---------------- merged f64-exact fixup for flagged rows ------------------
__global__ __launch_bounds__(256) void fixup_kernel(
    const int* __restrict__ fcnts, const int* __restrict__ flq,
    const int* __restrict__ flk, const double* __restrict__ xn,
    const double* __restrict__ W2q, const double* __restrict__ W2k,
    int* __restrict__ riQ, int* __restrict__ riK, double* __restrict__ rwQ,
    double* __restrict__ rwK) {
  __shared__ double xsh[1024];
  __shared__ double psh[256];
  __shared__ double ssh[128];
  const int which = blockIdx.y;
  const int* flist = which ? flk : flq;
  const double* W2 = which ? W2k : W2q;
  int* oidx = which ? riK : riQ;
  double* ow = which ? rwK : rwQ;
  const int tid = threadIdx.x;
  const int n = min(fcnts[which], MAXFLAG);
  for (int i = blockIdx.x; i < n; i += gridDim.x) {
    __syncthreads();
    const int rid = flist[i];
    const int t = rid & 4095, h = (rid >> 12) & 7, b = rid >> 15;
    const double* xr = xn + ((size_t)b * SEQ + t) * DIMM;
    for (int j = tid; j < DIMM; j += 256) xsh[j] = xr[j];
    __syncthreads();
    const int slot = tid >> 1, half = tid & 1;
    const double* w2r = W2 + (size_t)(h * NSLOTS + slot) * DIMM + half * 512;
    const double* xp = xsh + half * 512;
    double acc = 0.0;
#pragma unroll 8
    for (int d = 0; d < 512; d++) acc += xp[d] * w2r[d];
    psh[tid] = acc;
    __syncthreads();
    if (tid < 128) ssh[tid] = (psh[2 * tid] + psh[2 * tid + 1]) * SCALE64;
    __syncthreads();
    if (tid < 64) {
      const int lane = tid;
      double selv = -1e300; int seli = 0;
      double v0 = ssh[lane], v1 = ssh[lane + 64];
      for (int it = 0; it < 16; it++) {
        double m; int mi;
        if (v1 > v0) { m = v1; mi = lane + 64; } else { m = v0; mi = lane; }
#pragma unroll
        for (int off = 1; off < 64; off <<= 1) {
          const double om = __shfl_xor(m, off);
          const int oi = __shfl_xor(mi, off);
          if (om > m || (om == m && oi < mi)) { m = om; mi = oi; }
        }
        if (lane == it) { selv = m; seli = mi; }
        if (mi == lane) v0 = -1e300;
        if (mi == lane + 64) v1 = -1e300;
      }
      const double mx = __shfl(selv, 0);
      const float e = (lane < 16) ? expf((float)(selv - mx)) : 0.0f;
      double ss = (double)e;
      ss += __shfl_xor(ss, 1); ss += __shfl_xor(ss, 2);
      ss += __shfl_xor(ss, 4); ss += __shfl_xor(ss, 8);
      if (lane < 16) {
        ow[(size_t)rid * 16 + lane] = (double)e / ss;
        oidx[(size_t)rid * 16 + lane] = seli;
      }
    }
  }
}

// ------- dense per-chunk write delta (V f32, f64 accum, stable order) ------
__global__ __launch_bounds__(512) void delta64_kernel(
    const int* __restrict__ wi, const double* __restrict__ ww,
    const float* __restrict__ V, double* __restrict__ delta) {
  __shared__ short slot_sh[4096];
  __shared__ double w_sh[4096];
  __shared__ u16 list[4096];
  __shared__ int cnt[NSLOTS], off_[NSLOTS];
  const int bid = blockIdx.x;
  const int c = bid & 15, h = (bid >> 4) & 7, b = bid >> 7;
  const int tid = threadIdx.x;
  if (tid < NSLOTS) cnt[tid] = 0;
  __syncthreads();
  const size_t ebase = ((size_t)(b * 8 + h) * SEQ + (size_t)c * CHUNK) * 16;
#pragma unroll
  for (int i = 0; i < 8; i++) {
    const int e = tid + i * 512;
    const int s = wi[ebase + e];
    slot_sh[e] = (short)s;
    w_sh[e] = ww[ebase + e];
    atomicAdd(&cnt[s], 1);
  }
  __syncthreads();
  if (tid == 0) {
    int a = 0;
    for (int s = 0; s < NSLOTS; s++) { off_[s] = a; a += cnt[s]; }
  }
  __syncthreads();
  if (tid < NSLOTS) {
    int p = off_[tid];
    const short me = (short)tid;
    for (int e = 0; e < 4096; e++)
      if (slot_sh[e] == me) list[p++] = (u16)e;
  }
  __syncthreads();
  const int slot = tid >> 2, dbase = (tid & 3) * 32;
  double acc[32] = {};
  const int start = off_[slot], len = cnt[slot];
  const float* vbase =
      V + ((size_t)b * SEQ + (size_t)c * CHUNK) * DIMM + h * DH + dbase;
  for (int i = 0; i < len; i++) {
    const int e = list[start + i];
    const double w = w_sh[e];
    const float* vp = vbase + (size_t)(e >> 4) * DIMM;
#pragma unroll
    for (int d = 0; d < 32; d++) acc[d] += w * (double)vp[d];
  }
  double* dst = delta + ((size_t)bid * NSLOTS + slot) * DH + dbase;
#pragma unroll
  for (int d = 0; d < 32; d++) dst[d] = acc[d];
}

// --- fused local attention: f32 QK + f32 per-tile PV with f64 promote ------
// block = (b,c,h,rq of 8, heavy-first): 32 q-rows; thread (row, sub).
__global__ __launch_bounds__(256) void attn_fused(
    const float* __restrict__ Q, const float* __restrict__ Kb,
    const float* __restrict__ V, float* __restrict__ outb) {
  __shared__ float Qs[32][130];
  __shared__ float KVs[16][130];
  const int idx = blockIdx.x;
  const int rq = 7 - (idx & 7);  // heavy blocks dispatched first
  const int h = (idx >> 3) & 7, c = (idx >> 6) & 15, b = idx >> 10;
  const int tid = threadIdx.x;
  const size_t rowbase = (size_t)b * SEQ + (size_t)c * CHUNK;
  {
    const int r = tid >> 3, d0 = (tid & 7) * 16;
    const float* qp = Q + (rowbase + rq * 32 + r) * DIMM + h * DH + d0;
#pragma unroll
    for (int j = 0; j < 16; j++) Qs[r][d0 + j] = qp[j];
  }
  const int row = tid >> 3;
  const int sub = tid & 7;
  const int row_abs = rq * 32 + row;
  const int ntile = 2 * rq + 2;
  float pexp[16][2];
#pragma unroll
  for (int kt = 0; kt < 16; kt++) { pexp[kt][0] = -1e30f; pexp[kt][1] = -1e30f; }

  // ---- phase 1: QK scores, f32 vectorized dots (continuous path) ----
#pragma unroll
  for (int kt = 0; kt < 16; kt++) {
    if (kt < ntile) {
      __syncthreads();
      {
        const int r = tid >> 4, d0 = (tid & 15) * 8;
        const float* kp = Kb + (rowbase + kt * 16 + r) * DIMM + h * DH + d0;
#pragma unroll
        for (int j = 0; j < 8; j++) KVs[r][d0 + j] = kp[j];
      }
      __syncthreads();
#pragma unroll
      for (int kk = 0; kk < 2; kk++) {
        const int key = sub * 2 + kk;
        float sx = 0.f, sy = 0.f, sz = 0.f, sw = 0.f;
#pragma unroll
        for (int d = 0; d < 128; d += 4) {
          const float4 qv = *(const float4*)&Qs[row][d];
          const float4 kv = *(const float4*)&KVs[key][d];
          sx += qv.x * kv.x; sy += qv.y * kv.y;
          sz += qv.z * kv.z; sw += qv.w * kv.w;
        }
        const float s = (sx + sy) + (sz + sw);
        const int kabs = kt * 16 + key;
        pexp[kt][kk] = (kabs <= row_abs) ? s * (float)SCALE64 : -1e30f;
      }
    }
  }
  // ---- phase 2: softmax (8 lanes per row) ----
  float m = -1e30f;
#pragma unroll
  for (int kt = 0; kt < 16; kt++) {
    m = fmaxf(m, pexp[kt][0]); m = fmaxf(m, pexp[kt][1]);
  }
  m = fmaxf(m, __shfl_xor(m, 1));
  m = fmaxf(m, __shfl_xor(m, 2));
  m = fmaxf(m, __shfl_xor(m, 4));
  double ss = 0.0;
#pragma unroll
  for (int kt = 0; kt < 16; kt++) {
#pragma unroll
    for (int j = 0; j < 2; j++) {
      const float e = __expf(pexp[kt][j] - m);
      pexp[kt][j] = e;
      ss += (double)e;
    }
  }
  ss += __shfl_xor(ss, 1); ss += __shfl_xor(ss, 2); ss += __shfl_xor(ss, 4);
  const double inv = 1.0 / ss;
#pragma unroll
  for (int kt = 0; kt < 16; kt++) {
    pexp[kt][0] = (float)((double)pexp[kt][0] * inv);
    pexp[kt][1] = (float)((double)pexp[kt][1] * inv);
  }
  // ---- phase 3: PV, f32 per tile, f64 promote across tiles ----
  double acc[16] = {};
#pragma unroll
  for (int kt = 0; kt < 16; kt++) {
    if (kt < ntile) {
      __syncthreads();
      {
        const int r = tid >> 4, d0 = (tid & 15) * 8;
        const float* vp = V + (rowbase + kt * 16 + r) * DIMM + h * DH + d0;
#pragma unroll
        for (int j = 0; j < 8; j++) KVs[r][d0 + j] = vp[j];
      }
      __syncthreads();
      float ac[16] = {};
#pragma unroll
      for (int key = 0; key < 16; key++) {
        const int src = (tid & 56) | (key >> 1);
        const float pf = __shfl(pexp[kt][key & 1], src, 64);
        const float* vr = &KVs[key][sub * 16];
#pragma unroll
        for (int d = 0; d < 16; d++) ac[d] += pf * vr[d];
      }
#pragma unroll
      for (int d = 0; d < 16; d++) acc[d] += (double)ac[d];
    }
  }
  float* op = outb + (rowbase + row_abs) * DIMM + h * DH + sub * 16;
#pragma unroll
  for (int d = 0; d < 16; d++) op[d] = (float)acc[d];
}

// ------- sequential M recurrence, f64 state; emits split3(local+read) ------
__global__ __launch_bounds__(256) void recur64_kernel(
    const int* __restrict__ ri, const double* __restrict__ rw,
    const double* __restrict__ delta, const float* __restrict__ inb,
    u16* __restrict__ sh, u16* __restrict__ sm, u16* __restrict__ sl) {
  __shared__ double Msh[NSLOTS][17];
  const int bid = blockIdx.x;
  const int ds = bid & 7, h = (bid >> 3) & 7, b = bid >> 6;
  const int tid = threadIdx.x;
  for (int i = tid; i < NSLOTS * 17; i += 256) ((double*)Msh)[i] = 0.0;
  __syncthreads();
  for (int c = 0; c < NCHUNK; c++) {
    const size_t rbase =
        ((size_t)(b * 8 + h) * SEQ + (size_t)c * CHUNK + tid) * 16;
    double a[16] = {};
#pragma unroll
    for (int j = 0; j < 16; j++) {
      const int slot = ri[rbase + j];
      const double w = rw[rbase + j];
      const double* mp = &Msh[slot][0];
#pragma unroll
      for (int d = 0; d < 16; d++) a[d] += w * mp[d];
    }
    const size_t base = ((size_t)b * SEQ + (size_t)c * CHUNK + tid) * DIMM +
                        h * DH + ds * 16;
    const float* ip = inb + base;
    u16x4 rh[4], rm[4], rl[4];
#pragma unroll
    for (int q = 0; q < 4; q++) {
      float f0 = (float)((double)ip[q * 4 + 0] + a[q * 4 + 0]);
      float f1 = (float)((double)ip[q * 4 + 1] + a[q * 4 + 1]);
      float f2 = (float)((double)ip[q * 4 + 2] + a[q * 4 + 2]);
      float f3 = (float)((double)ip[q * 4 + 3] + a[q * 4 + 3]);
      split3s(f0, rh[q].x, rm[q].x, rl[q].x);
      split3s(f1, rh[q].y, rm[q].y, rl[q].y);
      split3s(f2, rh[q].z, rm[q].z, rl[q].z);
      split3s(f3, rh[q].w, rm[q].w, rl[q].w);
    }
#pragma unroll
    for (int q = 0; q < 4; q++) {
      ((u16x4*)(sh + base))[q] = rh[q];
      ((u16x4*)(sm + base))[q] = rm[q];
      ((u16x4*)(sl + base))[q] = rl[q];
    }
    __syncthreads();
    const int slot = tid >> 1, d8 = (tid & 1) * 8;
    const double* dp = delta +
        (((size_t)(b * 8 + h) * NCHUNK + c) * NSLOTS + slot) * DH + ds * 16 + d8;
#pragma unroll
    for (int d = 0; d < 8; d++)
      Msh[slot][d8 + d] = GAMMA64 * Msh[slot][d8 + d] + dp[d];
    __syncthreads();
  }
}

// ---------------- W[K][N] f32 -> WT[N][K] bf16 -----------------------------
__global__ void transconv_kernel(const float* __restrict__ W,
                                 u16* __restrict__ WT, int K, int N) {
  __shared__ float tile[32][33];
  const int n0 = blockIdx.x * 32, k0 = blockIdx.y * 32;
  const int tx = threadIdx.x, ty = threadIdx.y;
#pragma unroll
  for (int i = 0; i < 4; i++)
    tile[ty + 8 * i][tx] = W[(size_t)(k0 + ty + 8 * i) * N + n0 + tx];
  __syncthreads();
#pragma unroll
  for (int i = 0; i < 4; i++)
    WT[(size_t)(n0 + ty + 8 * i) * K + k0 + tx] = f2bf(tile[tx][ty + 8 * i]);
}

// ---- logits GEMM: 256x128 tile, BK=32, 512 thr, counted-vmcnt pipeline ----
__global__ __launch_bounds__(512) void gemm256_kernel(
    const u16* __restrict__ A, const u16* __restrict__ B, float* __restrict__ C,
    const float* __restrict__ bias, int M, int N, int K) {
  __shared__ u16 Ab[2][256 * 32];
  __shared__ u16 Bb[2][128 * 32];
  const int tid = threadIdx.x;
  const int lid = blockIdx.y * gridDim.x + blockIdx.x;
  const int npm = M / 256;
  const int ngrid = N / 128;
  const int GN = 16;
  const int ppg = GN * npm;
  const int gid = lid / ppg;
  const int first_n = gid * GN;
  const int gsz = min(GN, ngrid - first_n);
  const int local = lid - gid * ppg;
  const int bn = first_n + local % gsz;
  const int bm = local / gsz;
  const int w = tid >> 6, lane = tid & 63;
  const int wm = w >> 1, wn = w & 1;
  f32x4 acc[4][4] = {};
  const int srow = tid >> 2;
  const int scolb = (tid & 3) << 4;
  const char* Ag0 = (const char*)A + ((size_t)(bm * 256 + srow) * K) * 2 + scolb;
  const char* Ag1 =
      (const char*)A + ((size_t)(bm * 256 + 128 + srow) * K) * 2 + scolb;
  const char* Bg = (const char*)B + ((size_t)(bn * 128 + srow) * K) * 2 + scolb;
  const int wbase = (tid & 448) * 16;
  const int aoff = (wm * 64 + (lane & 15)) * 64 + (lane >> 4) * 16;
  const int boff = (wn * 64 + (lane & 15)) * 64 + (lane >> 4) * 16;
  const int NT = K / 32;

  gld16((char*)Ab[0] + wbase, Ag0);
  gld16((char*)Ab[0] + 8192 + wbase, Ag1);
  gld16((char*)Bb[0] + wbase, Bg);
  gld16((char*)Ab[1] + wbase, Ag0 + 64);
  gld16((char*)Ab[1] + 8192 + wbase, Ag1 + 64);
  gld16((char*)Bb[1] + wbase, Bg + 64);

  for (int t = 0; t < NT; t++) {
    const int p = t & 1;
    if (t == NT - 1)
      asm volatile("s_waitcnt vmcnt(0)" ::: "memory");
    else
      asm volatile("s_waitcnt vmcnt(3)" ::: "memory");
    __builtin_amdgcn_s_barrier();
    s16x8 af[4], bf[4];
    const char* pa = (const char*)Ab[p] + aoff;
    const char* pb = (const char*)Bb[p] + boff;
#pragma unroll
    for (int m = 0; m < 4; m++) af[m] = *(const s16x8*)(pa + m * 1024);
#pragma unroll
    for (int n = 0; n < 4; n++) bf[n] = *(const s16x8*)(pb + n * 1024);
#pragma unroll
    for (int m = 0; m < 4; m++)
#pragma unroll
      for (int n = 0; n < 4; n++) acc[m][n] = mfma16(af[m], bf[n], acc[m][n]);
    __builtin_amdgcn_s_barrier();
    __builtin_amdgcn_sched_barrier(0);
    if (t + 2 < NT) {
      const size_t kb = (size_t)(t + 2) * 64;
      gld16((char*)Ab[p] + wbase, Ag0 + kb);
      gld16((char*)Ab[p] + 8192 + wbase, Ag1 + kb);
      gld16((char*)Bb[p] + wbase, Bg + kb);
    }
  }
#pragma unroll
  for (int m = 0; m < 4; m++)
#pragma unroll
    for (int n = 0; n < 4; n++)
#pragma unroll
      for (int j = 0; j < 4; j++) {
        const int r = bm * 256 + wm * 64 + m * 16 + (lane >> 4) * 4 + j;
        const int c = bn * 128 + wn * 64 + n * 16 + (lane & 15);
        C[(size_t)r * N + c] = acc[m][n][j] + bias[c];
      }
}

extern "C" void kernel_launch(void* const* d_in, const int* in_sizes, int n_in,
                              void* d_out, int out_size, void* d_ws,
                              size_t ws_size, hipStream_t stream) {
  (void)in_sizes; (void)n_in; (void)out_size; (void)ws_size;
  const int* tokens = (const int*)d_in[0];
  const float* embed = (const float*)d_in[1];
  const float* Wq = (const float*)d_in[2];
  const float* Wk = (const float*)d_in[3];
  const float* Wv = (const float*)d_in[4];
  const float* Wo = (const float*)d_in[5];
  const float* slot_keys = (const float*)d_in[6];
  const float* ln_g = (const float*)d_in[7];
  const float* ln_b = (const float*)d_in[8];
  const float* fg = (const float*)d_in[9];
  const float* fb = (const float*)d_in[10];
  const float* Wout = (const float*)d_in[11];
  const float* bout = (const float*)d_in[12];
  float* out = (float*)d_out;

  char* p = (char*)d_ws;
  auto alloc = [&](size_t bytes) -> char* {
    char* r = p;
    p += (bytes + 255) & ~(size_t)255;
    return r;
  };
  const size_t RD = (size_t)NROWS * DIMM;
  double* hidden64 = (double*)alloc(RD * 8);
  double* xn64 = (double*)alloc(RD * 8);
  float* q32 = (float*)alloc(RD * 4);          // aliased as xnb at end
  float* k32 = (float*)alloc(RD * 4);          // k32+v32 aliased as WoutT
  float* v32 = (float*)alloc(RD * 4);
  float* local32 = (float*)alloc(RD * 4);
  double* delta64 =
      (double*)alloc((size_t)NB * NHEADS * NCHUNK * NSLOTS * DH * 8);
  int* ri = (int*)alloc((size_t)65536 * 16 * 4);
  int* wi = (int*)alloc((size_t)65536 * 16 * 4);
  double* rw64 = (double*)alloc((size_t)65536 * 16 * 8);
  double* ww64 = (double*)alloc((size_t)65536 * 16 * 8);
  u16* sAh = (u16*)alloc(RD * 2);
  u16* sAm = (u16*)alloc(RD * 2);
  u16* sAl = (u16*)alloc(RD * 2);
  u16* kBh = (u16*)alloc(RD * 2);
  u16* kBm = (u16*)alloc(RD * 2);
  u16* kBl = (u16*)alloc(RD * 2);
  u16* WTh = (u16*)alloc((size_t)8 * DIMM * DIMM * 2);
  u16* WTm = (u16*)alloc((size_t)8 * DIMM * DIMM * 2);
  u16* WTl = (u16*)alloc((size_t)8 * DIMM * DIMM * 2);
  double* W2q = (double*)alloc((size_t)2 * DIMM * DIMM * 8);
  double* W2k = (double*)alloc((size_t)2 * DIMM * DIMM * 8);
  const size_t SKE = (size_t)2 * NHEADS * NSLOTS * DH;
  u16* sk3h = (u16*)alloc(SKE * 2);
  u16* sk3m = (u16*)alloc(SKE * 2);
  u16* sk3l = (u16*)alloc(SKE * 2);
  float* S = (float*)alloc((size_t)2 * 65536 * NSLOTS * 4);
  int* fcnts = (int*)alloc(256);
  int* flq = (int*)alloc((size_t)MAXFLAG * 4);
  int* flk = (int*)alloc((size_t)MAXFLAG * 4);

  u16* xnb = (u16*)q32;
  u16* WoutT = (u16*)k32;

  const float* Wmats[4] = {Wq, Wk, Wv, Wo};
  for (int l = 0; l < 2; l++) {
    for (int w = 0; w < 4; w++) {
      const size_t o = ((size_t)l * 4 + w) * DIMM * DIMM;
      transconv3_kernel<<<dim3(DIMM / 32, DIMM / 32), dim3(32, 8), 0, stream>>>(
          Wmats[w] + (size_t)l * DIMM * DIMM, WTh + o, WTm + o, WTl + o, DIMM,
          DIMM);
    }
    const float* skl = slot_keys + (size_t)l * NHEADS * NSLOTS * DH;
    w2_kernel<<<1024, 256, 0, stream>>>(Wq + (size_t)l * DIMM * DIMM, skl,
                                        W2q + (size_t)l * DIMM * DIMM);
    w2_kernel<<<1024, 256, 0, stream>>>(Wk + (size_t)l * DIMM * DIMM, skl,
                                        W2k + (size_t)l * DIMM * DIMM);
  }
  cvt3_32_kernel<<<SKE / 1024, 256, 0, stream>>>(slot_keys, sk3h, sk3m, sk3l);

  embed64_kernel<<<NROWS, 256, 0, stream>>>(tokens, embed, hidden64);

  const dim3 g3(DIMM / 128, NROWS / 128);
  for (int l = 0; l < 2; l++) {
    const size_t oq = ((size_t)l * 4 + 0) * DIMM * DIMM;
    const size_t ok = ((size_t)l * 4 + 1) * DIMM * DIMM;
    const size_t ov = ((size_t)l * 4 + 2) * DIMM * DIMM;
    const size_t oo = ((size_t)l * 4 + 3) * DIMM * DIMM;
    const size_t sko = (size_t)l * NHEADS * NSLOTS * DH;
    ln64_kernel<0><<<NROWS, 256, 0, stream>>>(hidden64, ln_g + l * DIMM,
                                              ln_b + l * DIMM, xn64, sAh, sAm,
                                              sAl);
    gemm3d_kernel<false, float><<<g3, 256, 0, stream>>>(
        sAh, sAm, sAl, WTh + oq, WTm + oq, WTl + oq, q32, nullptr, NROWS, DIMM,
        DIMM);
    gemm3d_kernel<false, float><<<g3, 256, 0, stream>>>(
        sAh, sAm, sAl, WTh + ok, WTm + ok, WTl + ok, k32, nullptr, NROWS, DIMM,
        DIMM);
    gemm3d_kernel<false, float><<<g3, 256, 0, stream>>>(
        sAh, sAm, sAl, WTh + ov, WTm + ov, WTl + ov, v32, nullptr, NROWS, DIMM,
        DIMM);
    cvt3_32_kernel<<<RD / 1024, 256, 0, stream>>>(q32, sAh, sAm, sAl);
    cvt3_32_kernel<<<RD / 1024, 256, 0, stream>>>(k32, kBh, kBm, kBl);
    hipMemsetAsync(fcnts, 0, 8, stream);
    score3_kernel<<<dim3(32, 32), 256, 0, stream>>>(
        sAh, sAm, sAl, kBh, kBm, kBl, sk3h + sko, sk3m + sko, sk3l + sko, S);
    select_kernel<<<dim3(16384, 2), 256, 0, stream>>>(S, ri, wi, rw64, ww64,
                                                      fcnts, flq, flk);
    fixup_kernel<<<dim3(512, 2), 256, 0, stream>>>(
        fcnts, flq, flk, xn64, W2q + (size_t)l * DIMM * DIMM,
        W2k + (size_t)l * DIMM * DIMM, ri, wi, rw64, ww64);
    delta64_kernel<<<NB * NHEADS * NCHUNK, 512, 0, stream>>>(wi, ww64, v32,
                                                             delta64);
    attn_fused<<<NB * NCHUNK * NHEADS * 8, 256, 0, stream>>>(q32, k32, v32,
                                                             local32);
    recur64_kernel<<<NB * NHEADS * 8, 256, 0, stream>>>(ri, rw64, delta64,
                                                        local32, sAh, sAm,
                                                        sAl);
    gemm3d_kernel<true, double><<<g3, 256, 0, stream>>>(
        sAh, sAm, sAl, WTh + oo, WTm + oo, WTl + oo, hidden64, hidden64, NROWS,
        DIMM, DIMM);
  }
  transconv_kernel<<<dim3(NVOCAB / 32, DIMM / 32), dim3(32, 8), 0, stream>>>(
      Wout, WoutT, DIMM, NVOCAB);
  ln64_kernel<1><<<NROWS, 256, 0, stream>>>(hidden64, fg, fb, nullptr, xnb,
                                            nullptr, nullptr);
  gemm256_kernel<<<dim3(NVOCAB / 128, NROWS / 256), 512, 0, stream>>>(
      xnb, WoutT, out, bout, NROWS, NVOCAB, DIMM);
}

// Round 14
// 5130.257 us; speedup vs baseline: 1.2235x; 1.2235x over previous
//
#include <hip/hip_runtime.h>

#define DIMM 1024
#define NHEADS 8
#define DH 128
#define NSLOTS 128
#define CHUNK 256
#define NCHUNK 16
#define NB 2
#define SEQ 4096
#define NROWS (NB * SEQ)
#define NVOCAB 32000
#define GAMMA64 0.9
#define SCALE64 0.08838834764831845
#define TAU 1e-6f
#define MAXFLAG 65536

typedef unsigned short u16;
typedef __attribute__((ext_vector_type(4))) float f32x4;
typedef __attribute__((ext_vector_type(8))) short s16x8;

struct alignas(8) u16x4 { u16 x, y, z, w; };

__device__ __forceinline__ u16 f2bf(float f) {
  union { float f; unsigned u; } v; v.f = f;
  return (u16)((v.u + 0x7FFFu + ((v.u >> 16) & 1u)) >> 16);
}
__device__ __forceinline__ float bf2f(u16 u) {
  union { unsigned u; float f; } v; v.u = ((unsigned)u) << 16; return v.f;
}
// exact 3-way bf16 split of an f32 (h+m+l == x exactly)
__device__ __forceinline__ void split3s(float x, u16& h, u16& m, u16& l) {
  h = f2bf(x); float r = x - bf2f(h);
  m = f2bf(r); float r2 = r - bf2f(m);
  l = f2bf(r2);
}

__device__ __forceinline__ void gld16(void* lds, const void* g) {
  __builtin_amdgcn_global_load_lds(
      (const __attribute__((address_space(1))) unsigned*)g,
      (__attribute__((address_space(3))) unsigned*)lds, 16, 0, 0);
}
__device__ __forceinline__ f32x4 mfma16(s16x8 a, s16x8 b, f32x4 c) {
  return __builtin_amdgcn_mfma_f32_16x16x32_bf16(a, b, c, 0, 0, 0);
}

// ---------------- embedding gather -> f64 ----------------
__global__ __launch_bounds__(256) void embed64_kernel(
    const int* __restrict__ tok, const float* __restrict__ emb,
    double* __restrict__ hid) {
  const int row = blockIdx.x;
  const int t = tok[row];
  const float4 v = ((const float4*)(emb + (size_t)t * DIMM))[threadIdx.x];
  double* o = hid + (size_t)row * DIMM + threadIdx.x * 4;
  o[0] = (double)v.x; o[1] = (double)v.y; o[2] = (double)v.z; o[3] = (double)v.w;
}

// ------- f64 two-pass layernorm; MODE0: f64 xn + split3; MODE1: bf16 -------
template <int MODE>
__global__ __launch_bounds__(256) void ln64_kernel(
    const double* __restrict__ x, const float* __restrict__ g,
    const float* __restrict__ bb, double* __restrict__ o64,
    u16* __restrict__ oh, u16* __restrict__ om, u16* __restrict__ ol) {
  const int row = blockIdx.x, tid = threadIdx.x;
  const double* xr = x + (size_t)row * DIMM + tid * 4;
  const double v0 = xr[0], v1 = xr[1], v2 = xr[2], v3 = xr[3];
  __shared__ double red[4];
  double s1 = v0 + v1 + v2 + v3;
#pragma unroll
  for (int off = 32; off >= 1; off >>= 1) s1 += __shfl_xor(s1, off);
  if ((tid & 63) == 0) red[tid >> 6] = s1;
  __syncthreads();
  const double mu = (red[0] + red[1] + red[2] + red[3]) * (1.0 / DIMM);
  __syncthreads();
  const double d0 = v0 - mu, d1 = v1 - mu, d2 = v2 - mu, d3 = v3 - mu;
  double s2 = d0 * d0 + d1 * d1 + d2 * d2 + d3 * d3;
#pragma unroll
  for (int off = 32; off >= 1; off >>= 1) s2 += __shfl_xor(s2, off);
  if ((tid & 63) == 0) red[tid >> 6] = s2;
  __syncthreads();
  const double var = (red[0] + red[1] + red[2] + red[3]) * (1.0 / DIMM);
  const double rs = 1.0 / sqrt(var + 1e-5);
  const float4 g4 = ((const float4*)g)[tid];
  const float4 b4 = ((const float4*)bb)[tid];
  const double y0 = d0 * rs * (double)g4.x + (double)b4.x;
  const double y1 = d1 * rs * (double)g4.y + (double)b4.y;
  const double y2 = d2 * rs * (double)g4.z + (double)b4.z;
  const double y3 = d3 * rs * (double)g4.w + (double)b4.w;
  if (MODE == 0) {
    double* o = o64 + (size_t)row * DIMM + tid * 4;
    o[0] = y0; o[1] = y1; o[2] = y2; o[3] = y3;
    u16x4 rh, rm, rl;
    split3s((float)y0, rh.x, rm.x, rl.x);
    split3s((float)y1, rh.y, rm.y, rl.y);
    split3s((float)y2, rh.z, rm.z, rl.z);
    split3s((float)y3, rh.w, rm.w, rl.w);
    ((u16x4*)(oh + (size_t)row * DIMM))[tid] = rh;
    ((u16x4*)(om + (size_t)row * DIMM))[tid] = rm;
    ((u16x4*)(ol + (size_t)row * DIMM))[tid] = rl;
  } else {
    u16x4 r;
    r.x = f2bf((float)y0); r.y = f2bf((float)y1);
    r.z = f2bf((float)y2); r.w = f2bf((float)y3);
    ((u16x4*)(oh + (size_t)row * DIMM))[tid] = r;
  }
}

// ---------------- W[K][N] f32 -> WT[N][K] split3 bf16 ----------------
__global__ void transconv3_kernel(const float* __restrict__ W,
                                  u16* __restrict__ WTh, u16* __restrict__ WTm,
                                  u16* __restrict__ WTl, int K, int N) {
  __shared__ float tile[32][33];
  const int n0 = blockIdx.x * 32, k0 = blockIdx.y * 32;
  const int tx = threadIdx.x, ty = threadIdx.y;
#pragma unroll
  for (int i = 0; i < 4; i++)
    tile[ty + 8 * i][tx] = W[(size_t)(k0 + ty + 8 * i) * N + n0 + tx];
  __syncthreads();
#pragma unroll
  for (int i = 0; i < 4; i++) {
    u16 h, m, l;
    split3s(tile[tx][ty + 8 * i], h, m, l);
    const size_t o = (size_t)(n0 + ty + 8 * i) * K + k0 + tx;
    WTh[o] = h; WTm[o] = m; WTl[o] = l;
  }
}

// ---------------- f32 -> split3 bf16 elementwise ----------------
__global__ __launch_bounds__(256) void cvt3_32_kernel(
    const float* __restrict__ in, u16* __restrict__ oh, u16* __restrict__ om,
    u16* __restrict__ ol) {
  const size_t i = (size_t)blockIdx.x * 256 + threadIdx.x;
  const float4 v = ((const float4*)in)[i];
  u16x4 rh, rm, rl;
  split3s(v.x, rh.x, rm.x, rl.x); split3s(v.y, rh.y, rm.y, rl.y);
  split3s(v.z, rh.z, rm.z, rl.z); split3s(v.w, rh.w, rm.w, rl.w);
  ((u16x4*)oh)[i] = rh; ((u16x4*)om)[i] = rm; ((u16x4*)ol)[i] = rl;
}

// ---------------- combined slot-score weights: W2 (f64 exact) --------------
__global__ __launch_bounds__(256) void w2_kernel(const float* __restrict__ W,
                                                 const float* __restrict__ sk,
                                                 double* __restrict__ W2) {
  __shared__ float sksh[128];
  const int r = blockIdx.x, h = r >> 7;
  const int tid = threadIdx.x;
  if (tid < 128) sksh[tid] = sk[(size_t)r * DH + tid];
  __syncthreads();
  for (int d = tid; d < DIMM; d += 256) {
    const float* wrow = W + (size_t)d * DIMM + h * DH;
    double acc = 0.0;
#pragma unroll 8
    for (int j = 0; j < 128; j++) acc += (double)wrow[j] * (double)sksh[j];
    W2[(size_t)r * DIMM + d] = acc;
  }
}

// ------- split3 f32-faithful GEMM -> TC out: C = A @ BT^T (+res) ----------
template <bool RES, typename TC>
__global__ __launch_bounds__(256) void gemm3d_kernel(
    const u16* __restrict__ Ah, const u16* __restrict__ Am,
    const u16* __restrict__ Al, const u16* __restrict__ Bh,
    const u16* __restrict__ Bm, const u16* __restrict__ Bl,
    TC* __restrict__ C, const TC* __restrict__ Cres, int M, int N, int K) {
  __shared__ u16 lds[6 * 128 * 32];
  const int tid = threadIdx.x;
  const int bn = blockIdx.x, bm = blockIdx.y;
  const int wid = tid >> 6, lane = tid & 63;
  const int wr = (wid >> 1) * 64, wc = (wid & 1) * 64;
  f32x4 acc[4][4] = {};
  const int row0 = tid >> 2;
  const int colb = (tid & 3) << 4;
  const u16* Gs[6] = {Ah, Am, Al, Bh, Bm, Bl};
  const char* g0[6];
  const char* g1[6];
  char* lb[6];
#pragma unroll
  for (int i = 0; i < 6; i++) {
    const int rbase = (i < 3 ? bm : bn) * 128;
    g0[i] = (const char*)Gs[i] + ((size_t)(rbase + row0) * K) * 2 + colb;
    g1[i] = (const char*)Gs[i] + ((size_t)(rbase + row0 + 64) * K) * 2 + colb;
    lb[i] = (char*)lds + i * 8192 + (tid & 192) * 16;
  }
  const int fo = (lane & 15) * 64 + (lane >> 4) * 16;
  const char* paH = (const char*)lds + 0 + wr * 64 + fo;
  const char* paM = paH + 8192;
  const char* paL = paH + 16384;
  const char* pbH = (const char*)lds + 24576 + wc * 64 + fo;
  const char* pbM = pbH + 8192;
  const char* pbL = pbH + 16384;

  for (int k0 = 0; k0 < K; k0 += 32) {
    const size_t kb = (size_t)k0 * 2;
#pragma unroll
    for (int i = 0; i < 6; i++) {
      gld16(lb[i], g0[i] + kb);
      gld16(lb[i] + 4096, g1[i] + kb);
    }
    __syncthreads();
    s16x8 bh[4], bm_[4], bl[4];
#pragma unroll
    for (int n = 0; n < 4; n++) {
      bh[n] = *(const s16x8*)(pbH + n * 1024);
      bm_[n] = *(const s16x8*)(pbM + n * 1024);
      bl[n] = *(const s16x8*)(pbL + n * 1024);
    }
#pragma unroll
    for (int m = 0; m < 4; m++) {
      const s16x8 ah = *(const s16x8*)(paH + m * 1024);
      const s16x8 am = *(const s16x8*)(paM + m * 1024);
      const s16x8 al = *(const s16x8*)(paL + m * 1024);
#pragma unroll
      for (int n = 0; n < 4; n++) {
        f32x4 t = acc[m][n];
        t = mfma16(al, bh[n], t);
        t = mfma16(ah, bl[n], t);
        t = mfma16(am, bm_[n], t);
        t = mfma16(am, bh[n], t);
        t = mfma16(ah, bm_[n], t);
        t = mfma16(ah, bh[n], t);
        acc[m][n] = t;
      }
    }
    __syncthreads();
  }
#pragma unroll
  for (int m = 0; m < 4; m++)
#pragma unroll
    for (int n = 0; n < 4; n++)
#pragma unroll
      for (int j = 0; j < 4; j++) {
        const int r = bm * 128 + wr + m * 16 + (lane >> 4) * 4 + j;
        const int c = bn * 128 + wc + n * 16 + (lane & 15);
        TC v = (TC)acc[m][n][j];
        if (RES) v += Cres[(size_t)r * N + c];
        C[(size_t)r * N + c] = v;
      }
}

// ------- slot scores via split3 MFMA: S[which][rid][slot] (f32) ------------
__global__ __launch_bounds__(256) void score3_kernel(
    const u16* __restrict__ Qh, const u16* __restrict__ Qm,
    const u16* __restrict__ Ql, const u16* __restrict__ Kh3,
    const u16* __restrict__ Km3, const u16* __restrict__ Kl3,
    const u16* __restrict__ skh, const u16* __restrict__ skm,
    const u16* __restrict__ skl, float* __restrict__ S) {
  __shared__ u16 lds[6 * 128 * 32];
  const int tid = threadIdx.x;
  const int bm = blockIdx.x;
  const int y = blockIdx.y;
  const int which = y >> 4, b = (y >> 3) & 1, h = y & 7;
  const u16* Ah = which ? Kh3 : Qh;
  const u16* Am = which ? Km3 : Qm;
  const u16* Al = which ? Kl3 : Ql;
  const int wid = tid >> 6, lane = tid & 63;
  const int wr = (wid >> 1) * 64, wc = (wid & 1) * 64;
  f32x4 acc[4][4] = {};
  const int row0 = tid >> 2;
  const int colb = (tid & 3) << 4;
  const size_t arow = (size_t)(b * SEQ + bm * 128);
  const u16* Gs[6] = {Ah, Am, Al, skh, skm, skl};
  const char* g0[6];
  const char* g1[6];
  char* lb[6];
#pragma unroll
  for (int i = 0; i < 6; i++) {
    if (i < 3) {
      g0[i] = (const char*)Gs[i] + (arow + row0) * 2048 + h * 256 + colb;
      g1[i] = (const char*)Gs[i] + (arow + row0 + 64) * 2048 + h * 256 + colb;
    } else {
      g0[i] = (const char*)Gs[i] + ((size_t)h * 128 + row0) * 256 + colb;
      g1[i] = (const char*)Gs[i] + ((size_t)h * 128 + row0 + 64) * 256 + colb;
    }
    lb[i] = (char*)lds + i * 8192 + (tid & 192) * 16;
  }
  const int fo = (lane & 15) * 64 + (lane >> 4) * 16;
  const char* paH = (const char*)lds + 0 + wr * 64 + fo;
  const char* paM = paH + 8192;
  const char* paL = paH + 16384;
  const char* pbH = (const char*)lds + 24576 + wc * 64 + fo;
  const char* pbM = pbH + 8192;
  const char* pbL = pbH + 16384;

  for (int k0 = 0; k0 < DH; k0 += 32) {
    const size_t kb = (size_t)k0 * 2;
#pragma unroll
    for (int i = 0; i < 6; i++) {
      gld16(lb[i], g0[i] + kb);
      gld16(lb[i] + 4096, g1[i] + kb);
    }
    __syncthreads();
    s16x8 bh[4], bm_[4], bl[4];
#pragma unroll
    for (int n = 0; n < 4; n++) {
      bh[n] = *(const s16x8*)(pbH + n * 1024);
      bm_[n] = *(const s16x8*)(pbM + n * 1024);
      bl[n] = *(const s16x8*)(pbL + n * 1024);
    }
#pragma unroll
    for (int m = 0; m < 4; m++) {
      const s16x8 ah = *(const s16x8*)(paH + m * 1024);
      const s16x8 am = *(const s16x8*)(paM + m * 1024);
      const s16x8 al = *(const s16x8*)(paL + m * 1024);
#pragma unroll
      for (int n = 0; n < 4; n++) {
        f32x4 t = acc[m][n];
        t = mfma16(al, bh[n], t);
        t = mfma16(ah, bl[n], t);
        t = mfma16(am, bm_[n], t);
        t = mfma16(am, bh[n], t);
        t = mfma16(ah, bm_[n], t);
        t = mfma16(ah, bh[n], t);
        acc[m][n] = t;
      }
    }
    __syncthreads();
  }
  const size_t sbase =
      (size_t)which * 65536 + (size_t)(b * 8 + h) * 4096 + (size_t)bm * 128;
#pragma unroll
  for (int m = 0; m < 4; m++)
#pragma unroll
    for (int n = 0; n < 4; n++)
#pragma unroll
      for (int j = 0; j < 4; j++) {
        const int r = wr + m * 16 + (lane >> 4) * 4 + j;
        const int c = wc + n * 16 + (lane & 15);
        S[(sbase + r) * NSLOTS + c] = acc[m][n][j];
      }
}

// -------- top-16 selection on precomputed f32 scores + flagging ------------
__global__ __launch_bounds__(256) void select_kernel(
    const float* __restrict__ S, int* __restrict__ riQ, int* __restrict__ riK,
    double* __restrict__ rwQ, double* __restrict__ rwK,
    int* __restrict__ fcnts, int* __restrict__ flq, int* __restrict__ flk) {
  const int which = blockIdx.y;
  int* oidx = which ? riK : riQ;
  double* ow = which ? rwK : rwQ;
  int* fcnt = fcnts + which;
  int* flist = which ? flk : flq;
  const int wid = threadIdx.x >> 6, lane = threadIdx.x & 63;
  const int rid = blockIdx.x * 4 + wid;
  const float2 sv =
      *(const float2*)(S + ((size_t)which * 65536 + rid) * NSLOTS + lane * 2);
  const float sc = (float)SCALE64;
  float v0 = sv.x * sc, v1 = sv.y * sc;
  const int i0 = lane * 2, i1 = lane * 2 + 1;
  float selv = -1e30f; int seli = 0;
  for (int it = 0; it < 17; it++) {
    float m; int mi;
    if (v1 > v0) { m = v1; mi = i1; } else { m = v0; mi = i0; }
#pragma unroll
    for (int off = 1; off < 64; off <<= 1) {
      const float om = __shfl_xor(m, off);
      const int oi = __shfl_xor(mi, off);
      if (om > m || (om == m && oi < mi)) { m = om; mi = oi; }
    }
    if (lane == it) { selv = m; seli = mi; }
    if (mi == i0) v0 = -1e30f;
    if (mi == i1) v1 = -1e30f;
  }
  const float mx = __shfl(selv, 0);
  const float v15 = __shfl(selv, 15);
  const float v16 = __shfl(selv, 16);
  if (lane == 0 && (v15 - v16) < TAU) {
    const int p = atomicAdd(fcnt, 1);
    if (p < MAXFLAG) flist[p] = rid;
  }
  const float e = (lane < 16) ? expf(selv - mx) : 0.0f;
  double ss = (double)e;
  ss += __shfl_xor(ss, 1); ss += __shfl_xor(ss, 2);
  ss += __shfl_xor(ss, 4); ss += __shfl_xor(ss, 8);
  if (lane < 16) {
    ow[(size_t)rid * 16 + lane] = (double)e / ss;
    oidx[(size_t)rid * 16 + lane] = seli;
  }
}

// ---------------- merged f64-exact fixup for flagged rows ------------------
__global__ __launch_bounds__(256) void fixup_kernel(
    const int* __restrict__ fcnts, const int* __restrict__ flq,
    const int* __restrict__ flk, const double* __restrict__ xn,
    const double* __restrict__ W2q, const double* __restrict__ W2k,
    int* __restrict__ riQ, int* __restrict__ riK, double* __restrict__ rwQ,
    double* __restrict__ rwK) {
  __shared__ double xsh[1024];
  __shared__ double psh[256];
  __shared__ double ssh[128];
  const int which = blockIdx.y;
  const int* flist = which ? flk : flq;
  const double* W2 = which ? W2k : W2q;
  int* oidx = which ? riK : riQ;
  double* ow = which ? rwK : rwQ;
  const int tid = threadIdx.x;
  const int n = min(fcnts[which], MAXFLAG);
  for (int i = blockIdx.x; i < n; i += gridDim.x) {
    __syncthreads();
    const int rid = flist[i];
    const int t = rid & 4095, h = (rid >> 12) & 7, b = rid >> 15;
    const double* xr = xn + ((size_t)b * SEQ + t) * DIMM;
    for (int j = tid; j < DIMM; j += 256) xsh[j] = xr[j];
    __syncthreads();
    const int slot = tid >> 1, half = tid & 1;
    const double* w2r = W2 + (size_t)(h * NSLOTS + slot) * DIMM + half * 512;
    const double* xp = xsh + half * 512;
    double acc = 0.0;
#pragma unroll 8
    for (int d = 0; d < 512; d++) acc += xp[d] * w2r[d];
    psh[tid] = acc;
    __syncthreads();
    if (tid < 128) ssh[tid] = (psh[2 * tid] + psh[2 * tid + 1]) * SCALE64;
    __syncthreads();
    if (tid < 64) {
      const int lane = tid;
      double selv = -1e300; int seli = 0;
      double v0 = ssh[lane], v1 = ssh[lane + 64];
      for (int it = 0; it < 16; it++) {
        double m; int mi;
        if (v1 > v0) { m = v1; mi = lane + 64; } else { m = v0; mi = lane; }
#pragma unroll
        for (int off = 1; off < 64; off <<= 1) {
          const double om = __shfl_xor(m, off);
          const int oi = __shfl_xor(mi, off);
          if (om > m || (om == m && oi < mi)) { m = om; mi = oi; }
        }
        if (lane == it) { selv = m; seli = mi; }
        if (mi == lane) v0 = -1e300;
        if (mi == lane + 64) v1 = -1e300;
      }
      const double mx = __shfl(selv, 0);
      const float e = (lane < 16) ? expf((float)(selv - mx)) : 0.0f;
      double ss = (double)e;
      ss += __shfl_xor(ss, 1); ss += __shfl_xor(ss, 2);
      ss += __shfl_xor(ss, 4); ss += __shfl_xor(ss, 8);
      if (lane < 16) {
        ow[(size_t)rid * 16 + lane] = (double)e / ss;
        oidx[(size_t)rid * 16 + lane] = seli;
      }
    }
  }
}

// ------- dense per-chunk write delta (V f32, f64 accum, stable order) ------
__global__ __launch_bounds__(512) void delta64_kernel(
    const int* __restrict__ wi, const double* __restrict__ ww,
    const float* __restrict__ V, double* __restrict__ delta) {
  __shared__ short slot_sh[4096];
  __shared__ double w_sh[4096];
  __shared__ u16 list[4096];
  __shared__ int cnt[NSLOTS], off_[NSLOTS];
  const int bid = blockIdx.x;
  const int c = bid & 15, h = (bid >> 4) & 7, b = bid >> 7;
  const int tid = threadIdx.x;
  if (tid < NSLOTS) cnt[tid] = 0;
  __syncthreads();
  const size_t ebase = ((size_t)(b * 8 + h) * SEQ + (size_t)c * CHUNK) * 16;
#pragma unroll
  for (int i = 0; i < 8; i++) {
    const int e = tid + i * 512;
    const int s = wi[ebase + e];
    slot_sh[e] = (short)s;
    w_sh[e] = ww[ebase + e];
    atomicAdd(&cnt[s], 1);
  }
  __syncthreads();
  if (tid == 0) {
    int a = 0;
    for (int s = 0; s < NSLOTS; s++) { off_[s] = a; a += cnt[s]; }
  }
  __syncthreads();
  if (tid < NSLOTS) {
    int p = off_[tid];
    const short me = (short)tid;
    for (int e = 0; e < 4096; e++)
      if (slot_sh[e] == me) list[p++] = (u16)e;
  }
  __syncthreads();
  const int slot = tid >> 2, dbase = (tid & 3) * 32;
  double acc[32] = {};
  const int start = off_[slot], len = cnt[slot];
  const float* vbase =
      V + ((size_t)b * SEQ + (size_t)c * CHUNK) * DIMM + h * DH + dbase;
  for (int i = 0; i < len; i++) {
    const int e = list[start + i];
    const double w = w_sh[e];
    const float* vp = vbase + (size_t)(e >> 4) * DIMM;
#pragma unroll
    for (int d = 0; d < 32; d++) acc[d] += w * (double)vp[d];
  }
  double* dst = delta + ((size_t)bid * NSLOTS + slot) * DH + dbase;
#pragma unroll
  for (int d = 0; d < 32; d++) dst[d] = acc[d];
}

// --- fused local attention: f32 storage, f64 dots/accum, no S buffer -------
// (reverted to the round-11 form: 96 VGPR, simple sequential f64 dots)
__global__ __launch_bounds__(256) void attn_fused(
    const float* __restrict__ Q, const float* __restrict__ Kb,
    const float* __restrict__ V, float* __restrict__ outb) {
  __shared__ float Qs[32][130];
  __shared__ float KVs[16][130];
  const int idx = blockIdx.x;
  const int rq = idx & 7, h = (idx >> 3) & 7, c = (idx >> 6) & 15, b = idx >> 10;
  const int tid = threadIdx.x;
  const size_t rowbase = (size_t)b * SEQ + (size_t)c * CHUNK;
  {
    const int r = tid >> 3, d0 = (tid & 7) * 16;
    const float* qp = Q + (rowbase + rq * 32 + r) * DIMM + h * DH + d0;
#pragma unroll
    for (int j = 0; j < 16; j++) Qs[r][d0 + j] = qp[j];
  }
  const int row = tid >> 3;
  const int sub = tid & 7;
  const int row_abs = rq * 32 + row;
  const int ntile = 2 * rq + 2;
  float pexp[16][2];
#pragma unroll
  for (int kt = 0; kt < 16; kt++) { pexp[kt][0] = -1e30f; pexp[kt][1] = -1e30f; }

#pragma unroll
  for (int kt = 0; kt < 16; kt++) {
    if (kt < ntile) {
      __syncthreads();
      {
        const int r = tid >> 4, d0 = (tid & 15) * 8;
        const float* kp = Kb + (rowbase + kt * 16 + r) * DIMM + h * DH + d0;
#pragma unroll
        for (int j = 0; j < 8; j++) KVs[r][d0 + j] = kp[j];
      }
      __syncthreads();
#pragma unroll
      for (int kk = 0; kk < 2; kk++) {
        const int key = sub * 2 + kk;
        double s = 0.0;
#pragma unroll 8
        for (int d = 0; d < DH; d++)
          s += (double)Qs[row][d] * (double)KVs[key][d];
        const int kabs = kt * 16 + key;
        pexp[kt][kk] = (kabs <= row_abs) ? (float)(s * SCALE64) : -1e30f;
      }
    }
  }
  float m = -1e30f;
#pragma unroll
  for (int kt = 0; kt < 16; kt++) {
    m = fmaxf(m, pexp[kt][0]); m = fmaxf(m, pexp[kt][1]);
  }
  m = fmaxf(m, __shfl_xor(m, 1));
  m = fmaxf(m, __shfl_xor(m, 2));
  m = fmaxf(m, __shfl_xor(m, 4));
  double ss = 0.0;
#pragma unroll
  for (int kt = 0; kt < 16; kt++) {
#pragma unroll
    for (int j = 0; j < 2; j++) {
      const float e = __expf(pexp[kt][j] - m);
      pexp[kt][j] = e;
      ss += (double)e;
    }
  }
  ss += __shfl_xor(ss, 1); ss += __shfl_xor(ss, 2); ss += __shfl_xor(ss, 4);
  const double inv = 1.0 / ss;
#pragma unroll
  for (int kt = 0; kt < 16; kt++) {
    pexp[kt][0] = (float)((double)pexp[kt][0] * inv);
    pexp[kt][1] = (float)((double)pexp[kt][1] * inv);
  }
  double acc[16] = {};
#pragma unroll
  for (int kt = 0; kt < 16; kt++) {
    if (kt < ntile) {
      __syncthreads();
      {
        const int r = tid >> 4, d0 = (tid & 15) * 8;
        const float* vp = V + (rowbase + kt * 16 + r) * DIMM + h * DH + d0;
#pragma unroll
        for (int j = 0; j < 8; j++) KVs[r][d0 + j] = vp[j];
      }
      __syncthreads();
#pragma unroll
      for (int key = 0; key < 16; key++) {
        const int src = (tid & 56) | (key >> 1);
        const float pf = __shfl(pexp[kt][key & 1], src, 64);
        const double pd = (double)pf;
        const float* vr = &KVs[key][sub * 16];
#pragma unroll
        for (int d = 0; d < 16; d++) acc[d] += pd * (double)vr[d];
      }
    }
  }
  float* op = outb + (rowbase + row_abs) * DIMM + h * DH + sub * 16;
#pragma unroll
  for (int d = 0; d < 16; d++) op[d] = (float)acc[d];
}

// ------- sequential M recurrence, f64 state; emits split3(local+read) ------
__global__ __launch_bounds__(256) void recur64_kernel(
    const int* __restrict__ ri, const double* __restrict__ rw,
    const double* __restrict__ delta, const float* __restrict__ inb,
    u16* __restrict__ sh, u16* __restrict__ sm, u16* __restrict__ sl) {
  __shared__ double Msh[NSLOTS][17];
  const int bid = blockIdx.x;
  const int ds = bid & 7, h = (bid >> 3) & 7, b = bid >> 6;
  const int tid = threadIdx.x;
  for (int i = tid; i < NSLOTS * 17; i += 256) ((double*)Msh)[i] = 0.0;
  __syncthreads();
  for (int c = 0; c < NCHUNK; c++) {
    const size_t rbase =
        ((size_t)(b * 8 + h) * SEQ + (size_t)c * CHUNK + tid) * 16;
    double a[16] = {};
#pragma unroll
    for (int j = 0; j < 16; j++) {
      const int slot = ri[rbase + j];
      const double w = rw[rbase + j];
      const double* mp = &Msh[slot][0];
#pragma unroll
      for (int d = 0; d < 16; d++) a[d] += w * mp[d];
    }
    const size_t base = ((size_t)b * SEQ + (size_t)c * CHUNK + tid) * DIMM +
                        h * DH + ds * 16;
    const float* ip = inb + base;
    u16x4 rh[4], rm[4], rl[4];
#pragma unroll
    for (int q = 0; q < 4; q++) {
      float f0 = (float)((double)ip[q * 4 + 0] + a[q * 4 + 0]);
      float f1 = (float)((double)ip[q * 4 + 1] + a[q * 4 + 1]);
      float f2 = (float)((double)ip[q * 4 + 2] + a[q * 4 + 2]);
      float f3 = (float)((double)ip[q * 4 + 3] + a[q * 4 + 3]);
      split3s(f0, rh[q].x, rm[q].x, rl[q].x);
      split3s(f1, rh[q].y, rm[q].y, rl[q].y);
      split3s(f2, rh[q].z, rm[q].z, rl[q].z);
      split3s(f3, rh[q].w, rm[q].w, rl[q].w);
    }
#pragma unroll
    for (int q = 0; q < 4; q++) {
      ((u16x4*)(sh + base))[q] = rh[q];
      ((u16x4*)(sm + base))[q] = rm[q];
      ((u16x4*)(sl + base))[q] = rl[q];
    }
    __syncthreads();
    const int slot = tid >> 1, d8 = (tid & 1) * 8;
    const double* dp = delta +
        (((size_t)(b * 8 + h) * NCHUNK + c) * NSLOTS + slot) * DH + ds * 16 + d8;
#pragma unroll
    for (int d = 0; d < 8; d++)
      Msh[slot][d8 + d] = GAMMA64 * Msh[slot][d8 + d] + dp[d];
    __syncthreads();
  }
}

// ---------------- W[K][N] f32 -> WT[N][K] bf16 -----------------------------
__global__ void transconv_kernel(const float* __restrict__ W,
                                 u16* __restrict__ WT, int K, int N) {
  __shared__ float tile[32][33];
  const int n0 = blockIdx.x * 32, k0 = blockIdx.y * 32;
  const int tx = threadIdx.x, ty = threadIdx.y;
#pragma unroll
  for (int i = 0; i < 4; i++)
    tile[ty + 8 * i][tx] = W[(size_t)(k0 + ty + 8 * i) * N + n0 + tx];
  __syncthreads();
#pragma unroll
  for (int i = 0; i < 4; i++)
    WT[(size_t)(n0 + ty + 8 * i) * K + k0 + tx] = f2bf(tile[tx][ty + 8 * i]);
}

// ---- logits GEMM: 256x128 tile, BK=32, 512 thr, counted-vmcnt pipeline ----
__global__ __launch_bounds__(512) void gemm256_kernel(
    const u16* __restrict__ A, const u16* __restrict__ B, float* __restrict__ C,
    const float* __restrict__ bias, int M, int N, int K) {
  __shared__ u16 Ab[2][256 * 32];
  __shared__ u16 Bb[2][128 * 32];
  const int tid = threadIdx.x;
  const int lid = blockIdx.y * gridDim.x + blockIdx.x;
  const int npm = M / 256;
  const int ngrid = N / 128;
  const int GN = 16;
  const int ppg = GN * npm;
  const int gid = lid / ppg;
  const int first_n = gid * GN;
  const int gsz = min(GN, ngrid - first_n);
  const int local = lid - gid * ppg;
  const int bn = first_n + local % gsz;
  const int bm = local / gsz;
  const int w = tid >> 6, lane = tid & 63;
  const int wm = w >> 1, wn = w & 1;
  f32x4 acc[4][4] = {};
  const int srow = tid >> 2;
  const int scolb = (tid & 3) << 4;
  const char* Ag0 = (const char*)A + ((size_t)(bm * 256 + srow) * K) * 2 + scolb;
  const char* Ag1 =
      (const char*)A + ((size_t)(bm * 256 + 128 + srow) * K) * 2 + scolb;
  const char* Bg = (const char*)B + ((size_t)(bn * 128 + srow) * K) * 2 + scolb;
  const int wbase = (tid & 448) * 16;
  const int aoff = (wm * 64 + (lane & 15)) * 64 + (lane >> 4) * 16;
  const int boff = (wn * 64 + (lane & 15)) * 64 + (lane >> 4) * 16;
  const int NT = K / 32;

  gld16((char*)Ab[0] + wbase, Ag0);
  gld16((char*)Ab[0] + 8192 + wbase, Ag1);
  gld16((char*)Bb[0] + wbase, Bg);
  gld16((char*)Ab[1] + wbase, Ag0 + 64);
  gld16((char*)Ab[1] + 8192 + wbase, Ag1 + 64);
  gld16((char*)Bb[1] + wbase, Bg + 64);

  for (int t = 0; t < NT; t++) {
    const int p = t & 1;
    if (t == NT - 1)
      asm volatile("s_waitcnt vmcnt(0)" ::: "memory");
    else
      asm volatile("s_waitcnt vmcnt(3)" ::: "memory");
    __builtin_amdgcn_s_barrier();
    s16x8 af[4], bf[4];
    const char* pa = (const char*)Ab[p] + aoff;
    const char* pb = (const char*)Bb[p] + boff;
#pragma unroll
    for (int m = 0; m < 4; m++) af[m] = *(const s16x8*)(pa + m * 1024);
#pragma unroll
    for (int n = 0; n < 4; n++) bf[n] = *(const s16x8*)(pb + n * 1024);
#pragma unroll
    for (int m = 0; m < 4; m++)
#pragma unroll
      for (int n = 0; n < 4; n++) acc[m][n] = mfma16(af[m], bf[n], acc[m][n]);
    __builtin_amdgcn_s_barrier();
    __builtin_amdgcn_sched_barrier(0);
    if (t + 2 < NT) {
      const size_t kb = (size_t)(t + 2) * 64;
      gld16((char*)Ab[p] + wbase, Ag0 + kb);
      gld16((char*)Ab[p] + 8192 + wbase, Ag1 + kb);
      gld16((char*)Bb[p] + wbase, Bg + kb);
    }
  }
#pragma unroll
  for (int m = 0; m < 4; m++)
#pragma unroll
    for (int n = 0; n < 4; n++)
#pragma unroll
      for (int j = 0; j < 4; j++) {
        const int r = bm * 256 + wm * 64 + m * 16 + (lane >> 4) * 4 + j;
        const int c = bn * 128 + wn * 64 + n * 16 + (lane & 15);
        C[(size_t)r * N + c] = acc[m][n][j] + bias[c];
      }
}

extern "C" void kernel_launch(void* const* d_in, const int* in_sizes, int n_in,
                              void* d_out, int out_size, void* d_ws,
                              size_t ws_size, hipStream_t stream) {
  (void)in_sizes; (void)n_in; (void)out_size; (void)ws_size;
  const int* tokens = (const int*)d_in[0];
  const float* embed = (const float*)d_in[1];
  const float* Wq = (const float*)d_in[2];
  const float* Wk = (const float*)d_in[3];
  const float* Wv = (const float*)d_in[4];
  const float* Wo = (const float*)d_in[5];
  const float* slot_keys = (const float*)d_in[6];
  const float* ln_g = (const float*)d_in[7];
  const float* ln_b = (const float*)d_in[8];
  const float* fg = (const float*)d_in[9];
  const float* fb = (const float*)d_in[10];
  const float* Wout = (const float*)d_in[11];
  const float* bout = (const float*)d_in[12];
  float* out = (float*)d_out;

  char* p = (char*)d_ws;
  auto alloc = [&](size_t bytes) -> char* {
    char* r = p;
    p += (bytes + 255) & ~(size_t)255;
    return r;
  };
  const size_t RD = (size_t)NROWS * DIMM;
  double* hidden64 = (double*)alloc(RD * 8);
  double* xn64 = (double*)alloc(RD * 8);
  float* q32 = (float*)alloc(RD * 4);          // aliased as xnb at end
  float* k32 = (float*)alloc(RD * 4);          // k32+v32 aliased as WoutT
  float* v32 = (float*)alloc(RD * 4);
  float* local32 = (float*)alloc(RD * 4);
  double* delta64 =
      (double*)alloc((size_t)NB * NHEADS * NCHUNK * NSLOTS * DH * 8);
  int* ri = (int*)alloc((size_t)65536 * 16 * 4);
  int* wi = (int*)alloc((size_t)65536 * 16 * 4);
  double* rw64 = (double*)alloc((size_t)65536 * 16 * 8);
  double* ww64 = (double*)alloc((size_t)65536 * 16 * 8);
  u16* sAh = (u16*)alloc(RD * 2);
  u16* sAm = (u16*)alloc(RD * 2);
  u16* sAl = (u16*)alloc(RD * 2);
  u16* kBh = (u16*)alloc(RD * 2);
  u16* kBm = (u16*)alloc(RD * 2);
  u16* kBl = (u16*)alloc(RD * 2);
  u16* WTh = (u16*)alloc((size_t)8 * DIMM * DIMM * 2);
  u16* WTm = (u16*)alloc((size_t)8 * DIMM * DIMM * 2);
  u16* WTl = (u16*)alloc((size_t)8 * DIMM * DIMM * 2);
  double* W2q = (double*)alloc((size_t)2 * DIMM * DIMM * 8);
  double* W2k = (double*)alloc((size_t)2 * DIMM * DIMM * 8);
  const size_t SKE = (size_t)2 * NHEADS * NSLOTS * DH;
  u16* sk3h = (u16*)alloc(SKE * 2);
  u16* sk3m = (u16*)alloc(SKE * 2);
  u16* sk3l = (u16*)alloc(SKE * 2);
  float* S = (float*)alloc((size_t)2 * 65536 * NSLOTS * 4);
  int* fcnts = (int*)alloc(256);
  int* flq = (int*)alloc((size_t)MAXFLAG * 4);
  int* flk = (int*)alloc((size_t)MAXFLAG * 4);

  u16* xnb = (u16*)q32;
  u16* WoutT = (u16*)k32;

  const float* Wmats[4] = {Wq, Wk, Wv, Wo};
  for (int l = 0; l < 2; l++) {
    for (int w = 0; w < 4; w++) {
      const size_t o = ((size_t)l * 4 + w) * DIMM * DIMM;
      transconv3_kernel<<<dim3(DIMM / 32, DIMM / 32), dim3(32, 8), 0, stream>>>(
          Wmats[w] + (size_t)l * DIMM * DIMM, WTh + o, WTm + o, WTl + o, DIMM,
          DIMM);
    }
    const float* skl = slot_keys + (size_t)l * NHEADS * NSLOTS * DH;
    w2_kernel<<<1024, 256, 0, stream>>>(Wq + (size_t)l * DIMM * DIMM, skl,
                                        W2q + (size_t)l * DIMM * DIMM);
    w2_kernel<<<1024, 256, 0, stream>>>(Wk + (size_t)l * DIMM * DIMM, skl,
                                        W2k + (size_t)l * DIMM * DIMM);
  }
  cvt3_32_kernel<<<SKE / 1024, 256, 0, stream>>>(slot_keys, sk3h, sk3m, sk3l);

  embed64_kernel<<<NROWS, 256, 0, stream>>>(tokens, embed, hidden64);

  const dim3 g3(DIMM / 128, NROWS / 128);
  for (int l = 0; l < 2; l++) {
    const size_t oq = ((size_t)l * 4 + 0) * DIMM * DIMM;
    const size_t ok = ((size_t)l * 4 + 1) * DIMM * DIMM;
    const size_t ov = ((size_t)l * 4 + 2) * DIMM * DIMM;
    const size_t oo = ((size_t)l * 4 + 3) * DIMM * DIMM;
    const size_t sko = (size_t)l * NHEADS * NSLOTS * DH;
    ln64_kernel<0><<<NROWS, 256, 0, stream>>>(hidden64, ln_g + l * DIMM,
                                              ln_b + l * DIMM, xn64, sAh, sAm,
                                              sAl);
    gemm3d_kernel<false, float><<<g3, 256, 0, stream>>>(
        sAh, sAm, sAl, WTh + oq, WTm + oq, WTl + oq, q32, nullptr, NROWS, DIMM,
        DIMM);
    gemm3d_kernel<false, float><<<g3, 256, 0, stream>>>(
        sAh, sAm, sAl, WTh + ok, WTm + ok, WTl + ok, k32, nullptr, NROWS, DIMM,
        DIMM);
    gemm3d_kernel<false, float><<<g3, 256, 0, stream>>>(
        sAh, sAm, sAl, WTh + ov, WTm + ov, WTl + ov, v32, nullptr, NROWS, DIMM,
        DIMM);
    cvt3_32_kernel<<<RD / 1024, 256, 0, stream>>>(q32, sAh, sAm, sAl);
    cvt3_32_kernel<<<RD / 1024, 256, 0, stream>>>(k32, kBh, kBm, kBl);
    hipMemsetAsync(fcnts, 0, 8, stream);
    score3_kernel<<<dim3(32, 32), 256, 0, stream>>>(
        sAh, sAm, sAl, kBh, kBm, kBl, sk3h + sko, sk3m + sko, sk3l + sko, S);
    select_kernel<<<dim3(16384, 2), 256, 0, stream>>>(S, ri, wi, rw64, ww64,
                                                      fcnts, flq, flk);
    fixup_kernel<<<dim3(512, 2), 256, 0, stream>>>(
        fcnts, flq, flk, xn64, W2q + (size_t)l * DIMM * DIMM,
        W2k + (size_t)l * DIMM * DIMM, ri, wi, rw64, ww64);
    delta64_kernel<<<NB * NHEADS * NCHUNK, 512, 0, stream>>>(wi, ww64, v32,
                                                             delta64);
    attn_fused<<<NB * NCHUNK * NHEADS * 8, 256, 0, stream>>>(q32, k32, v32,
                                                             local32);
    recur64_kernel<<<NB * NHEADS * 8, 256, 0, stream>>>(ri, rw64, delta64,
                                                        local32, sAh, sAm,
                                                        sAl);
    gemm3d_kernel<true, double><<<g3, 256, 0, stream>>>(
        sAh, sAm, sAl, WTh + oo, WTm + oo, WTl + oo, hidden64, hidden64, NROWS,
        DIMM, DIMM);
  }
  transconv_kernel<<<dim3(NVOCAB / 32, DIMM / 32), dim3(32, 8), 0, stream>>>(
      Wout, WoutT, DIMM, NVOCAB);
  ln64_kernel<1><<<NROWS, 256, 0, stream>>>(hidden64, fg, fb, nullptr, xnb,
                                            nullptr, nullptr);
  gemm256_kernel<<<dim3(NVOCAB / 128, NROWS / 256), 512, 0, stream>>>(
      xnb, WoutT, out, bout, NROWS, NVOCAB, DIMM);
}

// Round 16
// 5080.666 us; speedup vs baseline: 1.2354x; 1.0098x over previous
//
#include <hip/hip_runtime.h>

#define DIMM 1024
#define NHEADS 8
#define DH 128
#define NSLOTS 128
#define CHUNK 256
#define NCHUNK 16
#define NB 2
#define SEQ 4096
#define NROWS (NB * SEQ)
#define NVOCAB 32000
#define GAMMA64 0.9
#define SCALE64 0.08838834764831845
#define TAU 1e-6f
#define MAXFLAG 65536

typedef unsigned short u16;
typedef __attribute__((ext_vector_type(4))) float f32x4;
typedef __attribute__((ext_vector_type(8))) short s16x8;

struct alignas(8) u16x4 { u16 x, y, z, w; };

__device__ __forceinline__ u16 f2bf(float f) {
  union { float f; unsigned u; } v; v.f = f;
  return (u16)((v.u + 0x7FFFu + ((v.u >> 16) & 1u)) >> 16);
}
__device__ __forceinline__ float bf2f(u16 u) {
  union { unsigned u; float f; } v; v.u = ((unsigned)u) << 16; return v.f;
}
// exact 3-way bf16 split of an f32 (h+m+l == x exactly)
__device__ __forceinline__ void split3s(float x, u16& h, u16& m, u16& l) {
  h = f2bf(x); float r = x - bf2f(h);
  m = f2bf(r); float r2 = r - bf2f(m);
  l = f2bf(r2);
}

__device__ __forceinline__ void gld16(void* lds, const void* g) {
  __builtin_amdgcn_global_load_lds(
      (const __attribute__((address_space(1))) unsigned*)g,
      (__attribute__((address_space(3))) unsigned*)lds, 16, 0, 0);
}
__device__ __forceinline__ f32x4 mfma16(s16x8 a, s16x8 b, f32x4 c) {
  return __builtin_amdgcn_mfma_f32_16x16x32_bf16(a, b, c, 0, 0, 0);
}

// ---------------- embedding gather -> f64 ----------------
__global__ __launch_bounds__(256) void embed64_kernel(
    const int* __restrict__ tok, const float* __restrict__ emb,
    double* __restrict__ hid) {
  const int row = blockIdx.x;
  const int t = tok[row];
  const float4 v = ((const float4*)(emb + (size_t)t * DIMM))[threadIdx.x];
  double* o = hid + (size_t)row * DIMM + threadIdx.x * 4;
  o[0] = (double)v.x; o[1] = (double)v.y; o[2] = (double)v.z; o[3] = (double)v.w;
}

// ------- f64 two-pass layernorm; MODE0: f64 xn + split3; MODE1: bf16 -------
template <int MODE>
__global__ __launch_bounds__(256) void ln64_kernel(
    const double* __restrict__ x, const float* __restrict__ g,
    const float* __restrict__ bb, double* __restrict__ o64,
    u16* __restrict__ oh, u16* __restrict__ om, u16* __restrict__ ol) {
  const int row = blockIdx.x, tid = threadIdx.x;
  const double* xr = x + (size_t)row * DIMM + tid * 4;
  const double v0 = xr[0], v1 = xr[1], v2 = xr[2], v3 = xr[3];
  __shared__ double red[4];
  double s1 = v0 + v1 + v2 + v3;
#pragma unroll
  for (int off = 32; off >= 1; off >>= 1) s1 += __shfl_xor(s1, off);
  if ((tid & 63) == 0) red[tid >> 6] = s1;
  __syncthreads();
  const double mu = (red[0] + red[1] + red[2] + red[3]) * (1.0 / DIMM);
  __syncthreads();
  const double d0 = v0 - mu, d1 = v1 - mu, d2 = v2 - mu, d3 = v3 - mu;
  double s2 = d0 * d0 + d1 * d1 + d2 * d2 + d3 * d3;
#pragma unroll
  for (int off = 32; off >= 1; off >>= 1) s2 += __shfl_xor(s2, off);
  if ((tid & 63) == 0) red[tid >> 6] = s2;
  __syncthreads();
  const double var = (red[0] + red[1] + red[2] + red[3]) * (1.0 / DIMM);
  const double rs = 1.0 / sqrt(var + 1e-5);
  const float4 g4 = ((const float4*)g)[tid];
  const float4 b4 = ((const float4*)bb)[tid];
  const double y0 = d0 * rs * (double)g4.x + (double)b4.x;
  const double y1 = d1 * rs * (double)g4.y + (double)b4.y;
  const double y2 = d2 * rs * (double)g4.z + (double)b4.z;
  const double y3 = d3 * rs * (double)g4.w + (double)b4.w;
  if (MODE == 0) {
    double* o = o64 + (size_t)row * DIMM + tid * 4;
    o[0] = y0; o[1] = y1; o[2] = y2; o[3] = y3;
    u16x4 rh, rm, rl;
    split3s((float)y0, rh.x, rm.x, rl.x);
    split3s((float)y1, rh.y, rm.y, rl.y);
    split3s((float)y2, rh.z, rm.z, rl.z);
    split3s((float)y3, rh.w, rm.w, rl.w);
    ((u16x4*)(oh + (size_t)row * DIMM))[tid] = rh;
    ((u16x4*)(om + (size_t)row * DIMM))[tid] = rm;
    ((u16x4*)(ol + (size_t)row * DIMM))[tid] = rl;
  } else {
    u16x4 r;
    r.x = f2bf((float)y0); r.y = f2bf((float)y1);
    r.z = f2bf((float)y2); r.w = f2bf((float)y3);
    ((u16x4*)(oh + (size_t)row * DIMM))[tid] = r;
  }
}

// ---------------- W[K][N] f32 -> WT[N][K] split3 bf16 ----------------
__global__ void transconv3_kernel(const float* __restrict__ W,
                                  u16* __restrict__ WTh, u16* __restrict__ WTm,
                                  u16* __restrict__ WTl, int K, int N) {
  __shared__ float tile[32][33];
  const int n0 = blockIdx.x * 32, k0 = blockIdx.y * 32;
  const int tx = threadIdx.x, ty = threadIdx.y;
#pragma unroll
  for (int i = 0; i < 4; i++)
    tile[ty + 8 * i][tx] = W[(size_t)(k0 + ty + 8 * i) * N + n0 + tx];
  __syncthreads();
#pragma unroll
  for (int i = 0; i < 4; i++) {
    u16 h, m, l;
    split3s(tile[tx][ty + 8 * i], h, m, l);
    const size_t o = (size_t)(n0 + ty + 8 * i) * K + k0 + tx;
    WTh[o] = h; WTm[o] = m; WTl[o] = l;
  }
}

// ---------------- f32 -> split3 bf16 elementwise ----------------
__global__ __launch_bounds__(256) void cvt3_32_kernel(
    const float* __restrict__ in, u16* __restrict__ oh, u16* __restrict__ om,
    u16* __restrict__ ol) {
  const size_t i = (size_t)blockIdx.x * 256 + threadIdx.x;
  const float4 v = ((const float4*)in)[i];
  u16x4 rh, rm, rl;
  split3s(v.x, rh.x, rm.x, rl.x); split3s(v.y, rh.y, rm.y, rl.y);
  split3s(v.z, rh.z, rm.z, rl.z); split3s(v.w, rh.w, rm.w, rl.w);
  ((u16x4*)oh)[i] = rh; ((u16x4*)om)[i] = rm; ((u16x4*)ol)[i] = rl;
}

// ---------------- combined slot-score weights: W2 (f64 exact) --------------
__global__ __launch_bounds__(256) void w2_kernel(const float* __restrict__ W,
                                                 const float* __restrict__ sk,
                                                 double* __restrict__ W2) {
  __shared__ float sksh[128];
  const int r = blockIdx.x, h = r >> 7;
  const int tid = threadIdx.x;
  if (tid < 128) sksh[tid] = sk[(size_t)r * DH + tid];
  __syncthreads();
  for (int d = tid; d < DIMM; d += 256) {
    const float* wrow = W + (size_t)d * DIMM + h * DH;
    double acc = 0.0;
#pragma unroll 8
    for (int j = 0; j < 128; j++) acc += (double)wrow[j] * (double)sksh[j];
    W2[(size_t)r * DIMM + d] = acc;
  }
}

// ------- split3 f32-faithful GEMM -> TC out: C = A @ BT^T (+res) ----------
template <bool RES, typename TC>
__global__ __launch_bounds__(256) void gemm3d_kernel(
    const u16* __restrict__ Ah, const u16* __restrict__ Am,
    const u16* __restrict__ Al, const u16* __restrict__ Bh,
    const u16* __restrict__ Bm, const u16* __restrict__ Bl,
    TC* __restrict__ C, const TC* __restrict__ Cres, int M, int N, int K) {
  __shared__ u16 lds[6 * 128 * 32];
  const int tid = threadIdx.x;
  const int bn = blockIdx.x, bm = blockIdx.y;
  const int wid = tid >> 6, lane = tid & 63;
  const int wr = (wid >> 1) * 64, wc = (wid & 1) * 64;
  f32x4 acc[4][4] = {};
  const int row0 = tid >> 2;
  const int colb = (tid & 3) << 4;
  const u16* Gs[6] = {Ah, Am, Al, Bh, Bm, Bl};
  const char* g0[6];
  const char* g1[6];
  char* lb[6];
#pragma unroll
  for (int i = 0; i < 6; i++) {
    const int rbase = (i < 3 ? bm : bn) * 128;
    g0[i] = (const char*)Gs[i] + ((size_t)(rbase + row0) * K) * 2 + colb;
    g1[i] = (const char*)Gs[i] + ((size_t)(rbase + row0 + 64) * K) * 2 + colb;
    lb[i] = (char*)lds + i * 8192 + (tid & 192) * 16;
  }
  const int fo = (lane & 15) * 64 + (lane >> 4) * 16;
  const char* paH = (const char*)lds + 0 + wr * 64 + fo;
  const char* paM = paH + 8192;
  const char* paL = paH + 16384;
  const char* pbH = (const char*)lds + 24576 + wc * 64 + fo;
  const char* pbM = pbH + 8192;
  const char* pbL = pbH + 16384;

  for (int k0 = 0; k0 < K; k0 += 32) {
    const size_t kb = (size_t)k0 * 2;
#pragma unroll
    for (int i = 0; i < 6; i++) {
      gld16(lb[i], g0[i] + kb);
      gld16(lb[i] + 4096, g1[i] + kb);
    }
    __syncthreads();
    s16x8 bh[4], bm_[4], bl[4];
#pragma unroll
    for (int n = 0; n < 4; n++) {
      bh[n] = *(const s16x8*)(pbH + n * 1024);
      bm_[n] = *(const s16x8*)(pbM + n * 1024);
      bl[n] = *(const s16x8*)(pbL + n * 1024);
    }
#pragma unroll
    for (int m = 0; m < 4; m++) {
      const s16x8 ah = *(const s16x8*)(paH + m * 1024);
      const s16x8 am = *(const s16x8*)(paM + m * 1024);
      const s16x8 al = *(const s16x8*)(paL + m * 1024);
#pragma unroll
      for (int n = 0; n < 4; n++) {
        f32x4 t = acc[m][n];
        t = mfma16(al, bh[n], t);
        t = mfma16(ah, bl[n], t);
        t = mfma16(am, bm_[n], t);
        t = mfma16(am, bh[n], t);
        t = mfma16(ah, bm_[n], t);
        t = mfma16(ah, bh[n], t);
        acc[m][n] = t;
      }
    }
    __syncthreads();
  }
#pragma unroll
  for (int m = 0; m < 4; m++)
#pragma unroll
    for (int n = 0; n < 4; n++)
#pragma unroll
      for (int j = 0; j < 4; j++) {
        const int r = bm * 128 + wr + m * 16 + (lane >> 4) * 4 + j;
        const int c = bn * 128 + wc + n * 16 + (lane & 15);
        TC v = (TC)acc[m][n][j];
        if (RES) v += Cres[(size_t)r * N + c];
        C[(size_t)r * N + c] = v;
      }
}

// ------- slot scores via split3 MFMA: S[which][rid][slot] (f32) ------------
__global__ __launch_bounds__(256) void score3_kernel(
    const u16* __restrict__ Qh, const u16* __restrict__ Qm,
    const u16* __restrict__ Ql, const u16* __restrict__ Kh3,
    const u16* __restrict__ Km3, const u16* __restrict__ Kl3,
    const u16* __restrict__ skh, const u16* __restrict__ skm,
    const u16* __restrict__ skl, float* __restrict__ S) {
  __shared__ u16 lds[6 * 128 * 32];
  const int tid = threadIdx.x;
  const int bm = blockIdx.x;
  const int y = blockIdx.y;
  const int which = y >> 4, b = (y >> 3) & 1, h = y & 7;
  const u16* Ah = which ? Kh3 : Qh;
  const u16* Am = which ? Km3 : Qm;
  const u16* Al = which ? Kl3 : Ql;
  const int wid = tid >> 6, lane = tid & 63;
  const int wr = (wid >> 1) * 64, wc = (wid & 1) * 64;
  f32x4 acc[4][4] = {};
  const int row0 = tid >> 2;
  const int colb = (tid & 3) << 4;
  const size_t arow = (size_t)(b * SEQ + bm * 128);
  const u16* Gs[6] = {Ah, Am, Al, skh, skm, skl};
  const char* g0[6];
  const char* g1[6];
  char* lb[6];
#pragma unroll
  for (int i = 0; i < 6; i++) {
    if (i < 3) {
      g0[i] = (const char*)Gs[i] + (arow + row0) * 2048 + h * 256 + colb;
      g1[i] = (const char*)Gs[i] + (arow + row0 + 64) * 2048 + h * 256 + colb;
    } else {
      g0[i] = (const char*)Gs[i] + ((size_t)h * 128 + row0) * 256 + colb;
      g1[i] = (const char*)Gs[i] + ((size_t)h * 128 + row0 + 64) * 256 + colb;
    }
    lb[i] = (char*)lds + i * 8192 + (tid & 192) * 16;
  }
  const int fo = (lane & 15) * 64 + (lane >> 4) * 16;
  const char* paH = (const char*)lds + 0 + wr * 64 + fo;
  const char* paM = paH + 8192;
  const char* paL = paH + 16384;
  const char* pbH = (const char*)lds + 24576 + wc * 64 + fo;
  const char* pbM = pbH + 8192;
  const char* pbL = pbH + 16384;

  for (int k0 = 0; k0 < DH; k0 += 32) {
    const size_t kb = (size_t)k0 * 2;
#pragma unroll
    for (int i = 0; i < 6; i++) {
      gld16(lb[i], g0[i] + kb);
      gld16(lb[i] + 4096, g1[i] + kb);
    }
    __syncthreads();
    s16x8 bh[4], bm_[4], bl[4];
#pragma unroll
    for (int n = 0; n < 4; n++) {
      bh[n] = *(const s16x8*)(pbH + n * 1024);
      bm_[n] = *(const s16x8*)(pbM + n * 1024);
      bl[n] = *(const s16x8*)(pbL + n * 1024);
    }
#pragma unroll
    for (int m = 0; m < 4; m++) {
      const s16x8 ah = *(const s16x8*)(paH + m * 1024);
      const s16x8 am = *(const s16x8*)(paM + m * 1024);
      const s16x8 al = *(const s16x8*)(paL + m * 1024);
#pragma unroll
      for (int n = 0; n < 4; n++) {
        f32x4 t = acc[m][n];
        t = mfma16(al, bh[n], t);
        t = mfma16(ah, bl[n], t);
        t = mfma16(am, bm_[n], t);
        t = mfma16(am, bh[n], t);
        t = mfma16(ah, bm_[n], t);
        t = mfma16(ah, bh[n], t);
        acc[m][n] = t;
      }
    }
    __syncthreads();
  }
  const size_t sbase =
      (size_t)which * 65536 + (size_t)(b * 8 + h) * 4096 + (size_t)bm * 128;
#pragma unroll
  for (int m = 0; m < 4; m++)
#pragma unroll
    for (int n = 0; n < 4; n++)
#pragma unroll
      for (int j = 0; j < 4; j++) {
        const int r = wr + m * 16 + (lane >> 4) * 4 + j;
        const int c = wc + n * 16 + (lane & 15);
        S[(sbase + r) * NSLOTS + c] = acc[m][n][j];
      }
}

// -------- top-16 selection on precomputed f32 scores + flagging ------------
__global__ __launch_bounds__(256) void select_kernel(
    const float* __restrict__ S, int* __restrict__ riQ, int* __restrict__ riK,
    double* __restrict__ rwQ, double* __restrict__ rwK,
    int* __restrict__ fcnts, int* __restrict__ flq, int* __restrict__ flk) {
  const int which = blockIdx.y;
  int* oidx = which ? riK : riQ;
  double* ow = which ? rwK : rwQ;
  int* fcnt = fcnts + which;
  int* flist = which ? flk : flq;
  const int wid = threadIdx.x >> 6, lane = threadIdx.x & 63;
  const int rid = blockIdx.x * 4 + wid;
  const float2 sv =
      *(const float2*)(S + ((size_t)which * 65536 + rid) * NSLOTS + lane * 2);
  const float sc = (float)SCALE64;
  float v0 = sv.x * sc, v1 = sv.y * sc;
  const int i0 = lane * 2, i1 = lane * 2 + 1;
  float selv = -1e30f; int seli = 0;
  for (int it = 0; it < 17; it++) {
    float m; int mi;
    if (v1 > v0) { m = v1; mi = i1; } else { m = v0; mi = i0; }
#pragma unroll
    for (int off = 1; off < 64; off <<= 1) {
      const float om = __shfl_xor(m, off);
      const int oi = __shfl_xor(mi, off);
      if (om > m || (om == m && oi < mi)) { m = om; mi = oi; }
    }
    if (lane == it) { selv = m; seli = mi; }
    if (mi == i0) v0 = -1e30f;
    if (mi == i1) v1 = -1e30f;
  }
  const float mx = __shfl(selv, 0);
  const float v15 = __shfl(selv, 15);
  const float v16 = __shfl(selv, 16);
  if (lane == 0 && (v15 - v16) < TAU) {
    const int p = atomicAdd(fcnt, 1);
    if (p < MAXFLAG) flist[p] = rid;
  }
  const float e = (lane < 16) ? expf(selv - mx) : 0.0f;
  double ss = (double)e;
  ss += __shfl_xor(ss, 1); ss += __shfl_xor(ss, 2);
  ss += __shfl_xor(ss, 4); ss += __shfl_xor(ss, 8);
  if (lane < 16) {
    ow[(size_t)rid * 16 + lane] = (double)e / ss;
    oidx[(size_t)rid * 16 + lane] = seli;
  }
}

// ---------------- merged f64-exact fixup for flagged rows ------------------
__global__ __launch_bounds__(256) void fixup_kernel(
    const int* __restrict__ fcnts, const int* __restrict__ flq,
    const int* __restrict__ flk, const double* __restrict__ xn,
    const double* __restrict__ W2q, const double* __restrict__ W2k,
    int* __restrict__ riQ, int* __restrict__ riK, double* __restrict__ rwQ,
    double* __restrict__ rwK) {
  __shared__ double xsh[1024];
  __shared__ double psh[256];
  __shared__ double ssh[128];
  const int which = blockIdx.y;
  const int* flist = which ? flk : flq;
  const double* W2 = which ? W2k : W2q;
  int* oidx = which ? riK : riQ;
  double* ow = which ? rwK : rwQ;
  const int tid = threadIdx.x;
  const int n = min(fcnts[which], MAXFLAG);
  for (int i = blockIdx.x; i < n; i += gridDim.x) {
    __syncthreads();
    const int rid = flist[i];
    const int t = rid & 4095, h = (rid >> 12) & 7, b = rid >> 15;
    const double* xr = xn + ((size_t)b * SEQ + t) * DIMM;
    for (int j = tid; j < DIMM; j += 256) xsh[j] = xr[j];
    __syncthreads();
    const int slot = tid >> 1, half = tid & 1;
    const double* w2r = W2 + (size_t)(h * NSLOTS + slot) * DIMM + half * 512;
    const double* xp = xsh + half * 512;
    double acc = 0.0;
#pragma unroll 8
    for (int d = 0; d < 512; d++) acc += xp[d] * w2r[d];
    psh[tid] = acc;
    __syncthreads();
    if (tid < 128) ssh[tid] = (psh[2 * tid] + psh[2 * tid + 1]) * SCALE64;
    __syncthreads();
    if (tid < 64) {
      const int lane = tid;
      double selv = -1e300; int seli = 0;
      double v0 = ssh[lane], v1 = ssh[lane + 64];
      for (int it = 0; it < 16; it++) {
        double m; int mi;
        if (v1 > v0) { m = v1; mi = lane + 64; } else { m = v0; mi = lane; }
#pragma unroll
        for (int off = 1; off < 64; off <<= 1) {
          const double om = __shfl_xor(m, off);
          const int oi = __shfl_xor(mi, off);
          if (om > m || (om == m && oi < mi)) { m = om; mi = oi; }
        }
        if (lane == it) { selv = m; seli = mi; }
        if (mi == lane) v0 = -1e300;
        if (mi == lane + 64) v1 = -1e300;
      }
      const double mx = __shfl(selv, 0);
      const float e = (lane < 16) ? expf((float)(selv - mx)) : 0.0f;
      double ss = (double)e;
      ss += __shfl_xor(ss, 1); ss += __shfl_xor(ss, 2);
      ss += __shfl_xor(ss, 4); ss += __shfl_xor(ss, 8);
      if (lane < 16) {
        ow[(size_t)rid * 16 + lane] = (double)e / ss;
        oidx[(size_t)rid * 16 + lane] = seli;
      }
    }
  }
}

// ------- dense per-chunk write delta (V f32, f64 accum, stable order) ------
__global__ __launch_bounds__(512) void delta64_kernel(
    const int* __restrict__ wi, const double* __restrict__ ww,
    const float* __restrict__ V, double* __restrict__ delta) {
  __shared__ short slot_sh[4096];
  __shared__ double w_sh[4096];
  __shared__ u16 list[4096];
  __shared__ int cnt[NSLOTS], off_[NSLOTS];
  const int bid = blockIdx.x;
  const int c = bid & 15, h = (bid >> 4) & 7, b = bid >> 7;
  const int tid = threadIdx.x;
  if (tid < NSLOTS) cnt[tid] = 0;
  __syncthreads();
  const size_t ebase = ((size_t)(b * 8 + h) * SEQ + (size_t)c * CHUNK) * 16;
#pragma unroll
  for (int i = 0; i < 8; i++) {
    const int e = tid + i * 512;
    const int s = wi[ebase + e];
    slot_sh[e] = (short)s;
    w_sh[e] = ww[ebase + e];
    atomicAdd(&cnt[s], 1);
  }
  __syncthreads();
  if (tid == 0) {
    int a = 0;
    for (int s = 0; s < NSLOTS; s++) { off_[s] = a; a += cnt[s]; }
  }
  __syncthreads();
  if (tid < NSLOTS) {
    int p = off_[tid];
    const short me = (short)tid;
    for (int e = 0; e < 4096; e++)
      if (slot_sh[e] == me) list[p++] = (u16)e;
  }
  __syncthreads();
  const int slot = tid >> 2, dbase = (tid & 3) * 32;
  double acc[32] = {};
  const int start = off_[slot], len = cnt[slot];
  const float* vbase =
      V + ((size_t)b * SEQ + (size_t)c * CHUNK) * DIMM + h * DH + dbase;
  for (int i = 0; i < len; i++) {
    const int e = list[start + i];
    const double w = w_sh[e];
    const float* vp = vbase + (size_t)(e >> 4) * DIMM;
#pragma unroll
    for (int d = 0; d < 32; d++) acc[d] += w * (double)vp[d];
  }
  double* dst = delta + ((size_t)bid * NSLOTS + slot) * DH + dbase;
#pragma unroll
  for (int d = 0; d < 32; d++) dst[d] = acc[d];
}

// --- fused local attention: f32 storage, f64 dots/accum (r14 exact) --------
__global__ __launch_bounds__(256) void attn_fused(
    const float* __restrict__ Q, const float* __restrict__ Kb,
    const float* __restrict__ V, float* __restrict__ outb) {
  __shared__ float Qs[32][130];
  __shared__ float KVs[16][130];
  const int idx = blockIdx.x;
  const int rq = idx & 7, h = (idx >> 3) & 7, c = (idx >> 6) & 15, b = idx >> 10;
  const int tid = threadIdx.x;
  const size_t rowbase = (size_t)b * SEQ + (size_t)c * CHUNK;
  {
    const int r = tid >> 3, d0 = (tid & 7) * 16;
    const float* qp = Q + (rowbase + rq * 32 + r) * DIMM + h * DH + d0;
#pragma unroll
    for (int j = 0; j < 16; j++) Qs[r][d0 + j] = qp[j];
  }
  const int row = tid >> 3;
  const int sub = tid & 7;
  const int row_abs = rq * 32 + row;
  const int ntile = 2 * rq + 2;
  float pexp[16][2];
#pragma unroll
  for (int kt = 0; kt < 16; kt++) { pexp[kt][0] = -1e30f; pexp[kt][1] = -1e30f; }

#pragma unroll
  for (int kt = 0; kt < 16; kt++) {
    if (kt < ntile) {
      __syncthreads();
      {
        const int r = tid >> 4, d0 = (tid & 15) * 8;
        const float* kp = Kb + (rowbase + kt * 16 + r) * DIMM + h * DH + d0;
#pragma unroll
        for (int j = 0; j < 8; j++) KVs[r][d0 + j] = kp[j];
      }
      __syncthreads();
#pragma unroll
      for (int kk = 0; kk < 2; kk++) {
        const int key = sub * 2 + kk;
        double s = 0.0;
#pragma unroll 8
        for (int d = 0; d < DH; d++)
          s += (double)Qs[row][d] * (double)KVs[key][d];
        const int kabs = kt * 16 + key;
        pexp[kt][kk] = (kabs <= row_abs) ? (float)(s * SCALE64) : -1e30f;
      }
    }
  }
  float m = -1e30f;
#pragma unroll
  for (int kt = 0; kt < 16; kt++) {
    m = fmaxf(m, pexp[kt][0]); m = fmaxf(m, pexp[kt][1]);
  }
  m = fmaxf(m, __shfl_xor(m, 1));
  m = fmaxf(m, __shfl_xor(m, 2));
  m = fmaxf(m, __shfl_xor(m, 4));
  double ss = 0.0;
#pragma unroll
  for (int kt = 0; kt < 16; kt++) {
#pragma unroll
    for (int j = 0; j < 2; j++) {
      const float e = __expf(pexp[kt][j] - m);
      pexp[kt][j] = e;
      ss += (double)e;
    }
  }
  ss += __shfl_xor(ss, 1); ss += __shfl_xor(ss, 2); ss += __shfl_xor(ss, 4);
  const double inv = 1.0 / ss;
#pragma unroll
  for (int kt = 0; kt < 16; kt++) {
    pexp[kt][0] = (float)((double)pexp[kt][0] * inv);
    pexp[kt][1] = (float)((double)pexp[kt][1] * inv);
  }
  double acc[16] = {};
#pragma unroll
  for (int kt = 0; kt < 16; kt++) {
    if (kt < ntile) {
      __syncthreads();
      {
        const int r = tid >> 4, d0 = (tid & 15) * 8;
        const float* vp = V + (rowbase + kt * 16 + r) * DIMM + h * DH + d0;
#pragma unroll
        for (int j = 0; j < 8; j++) KVs[r][d0 + j] = vp[j];
      }
      __syncthreads();
#pragma unroll
      for (int key = 0; key < 16; key++) {
        const int src = (tid & 56) | (key >> 1);
        const float pf = __shfl(pexp[kt][key & 1], src, 64);
        const double pd = (double)pf;
        const float* vr = &KVs[key][sub * 16];
#pragma unroll
        for (int d = 0; d < 16; d++) acc[d] += pd * (double)vr[d];
      }
    }
  }
  float* op = outb + (rowbase + row_abs) * DIMM + h * DH + sub * 16;
#pragma unroll
  for (int d = 0; d < 16; d++) op[d] = (float)acc[d];
}

// ------- sequential M recurrence, f64 state; emits split3(local+read) ------
__global__ __launch_bounds__(256) void recur64_kernel(
    const int* __restrict__ ri, const double* __restrict__ rw,
    const double* __restrict__ delta, const float* __restrict__ inb,
    u16* __restrict__ sh, u16* __restrict__ sm, u16* __restrict__ sl) {
  __shared__ double Msh[NSLOTS][17];
  const int bid = blockIdx.x;
  const int ds = bid & 7, h = (bid >> 3) & 7, b = bid >> 6;
  const int tid = threadIdx.x;
  for (int i = tid; i < NSLOTS * 17; i += 256) ((double*)Msh)[i] = 0.0;
  __syncthreads();
  for (int c = 0; c < NCHUNK; c++) {
    const size_t rbase =
        ((size_t)(b * 8 + h) * SEQ + (size_t)c * CHUNK + tid) * 16;
    double a[16] = {};
#pragma unroll
    for (int j = 0; j < 16; j++) {
      const int slot = ri[rbase + j];
      const double w = rw[rbase + j];
      const double* mp = &Msh[slot][0];
#pragma unroll
      for (int d = 0; d < 16; d++) a[d] += w * mp[d];
    }
    const size_t base = ((size_t)b * SEQ + (size_t)c * CHUNK + tid) * DIMM +
                        h * DH + ds * 16;
    const float* ip = inb + base;
    u16x4 rh[4], rm[4], rl[4];
#pragma unroll
    for (int q = 0; q < 4; q++) {
      float f0 = (float)((double)ip[q * 4 + 0] + a[q * 4 + 0]);
      float f1 = (float)((double)ip[q * 4 + 1] + a[q * 4 + 1]);
      float f2 = (float)((double)ip[q * 4 + 2] + a[q * 4 + 2]);
      float f3 = (float)((double)ip[q * 4 + 3] + a[q * 4 + 3]);
      split3s(f0, rh[q].x, rm[q].x, rl[q].x);
      split3s(f1, rh[q].y, rm[q].y, rl[q].y);
      split3s(f2, rh[q].z, rm[q].z, rl[q].z);
      split3s(f3, rh[q].w, rm[q].w, rl[q].w);
    }
#pragma unroll
    for (int q = 0; q < 4; q++) {
      ((u16x4*)(sh + base))[q] = rh[q];
      ((u16x4*)(sm + base))[q] = rm[q];
      ((u16x4*)(sl + base))[q] = rl[q];
    }
    __syncthreads();
    const int slot = tid >> 1, d8 = (tid & 1) * 8;
    const double* dp = delta +
        (((size_t)(b * 8 + h) * NCHUNK + c) * NSLOTS + slot) * DH + ds * 16 + d8;
#pragma unroll
    for (int d = 0; d < 8; d++)
      Msh[slot][d8 + d] = GAMMA64 * Msh[slot][d8 + d] + dp[d];
    __syncthreads();
  }
}

// ---------------- W[K][N] f32 -> WT[N][K] bf16 -----------------------------
__global__ void transconv_kernel(const float* __restrict__ W,
                                 u16* __restrict__ WT, int K, int N) {
  __shared__ float tile[32][33];
  const int n0 = blockIdx.x * 32, k0 = blockIdx.y * 32;
  const int tx = threadIdx.x, ty = threadIdx.y;
#pragma unroll
  for (int i = 0; i < 4; i++)
    tile[ty + 8 * i][tx] = W[(size_t)(k0 + ty + 8 * i) * N + n0 + tx];
  __syncthreads();
#pragma unroll
  for (int i = 0; i < 4; i++)
    WT[(size_t)(n0 + ty + 8 * i) * K + k0 + tx] = f2bf(tile[tx][ty + 8 * i]);
}

// ---- logits GEMM: 256x128 tile, counted-vmcnt + XCD-chunked block remap ---
__global__ __launch_bounds__(512) void gemm256_kernel(
    const u16* __restrict__ A, const u16* __restrict__ B, float* __restrict__ C,
    const float* __restrict__ bias, int M, int N, int K) {
  __shared__ u16 Ab[2][256 * 32];
  __shared__ u16 Bb[2][128 * 32];
  const int tid = threadIdx.x;
  const int lid = blockIdx.y * gridDim.x + blockIdx.x;
  const int npm = M / 256;            // 32
  const int ngrid = N / 128;          // 250
  const int GN = 16;
  const int ppg = GN * npm;           // 512
  const int gid = lid / ppg;
  const int first_n = gid * GN;
  const int gsz = min(GN, ngrid - first_n);
  const int local = lid - gid * ppg;
  int bn, bm;
  if (gsz == GN) {
    const int xs = local & 7;         // XCD slot under round-robin dispatch
    const int idx = local >> 3;       // 0..63
    bm = xs * 4 + (idx & 3);          // 4 contiguous bm per XCD
    bn = first_n + (idx >> 2);
  } else {
    bn = first_n + local % gsz;
    bm = local / gsz;
  }
  const int w = tid >> 6, lane = tid & 63;
  const int wm = w >> 1, wn = w & 1;
  f32x4 acc[4][4] = {};
  const int srow = tid >> 2;
  const int scolb = (tid & 3) << 4;
  const char* Ag0 = (const char*)A + ((size_t)(bm * 256 + srow) * K) * 2 + scolb;
  const char* Ag1 =
      (const char*)A + ((size_t)(bm * 256 + 128 + srow) * K) * 2 + scolb;
  const char* Bg = (const char*)B + ((size_t)(bn * 128 + srow) * K) * 2 + scolb;
  const int wbase = (tid & 448) * 16;
  const int aoff = (wm * 64 + (lane & 15)) * 64 + (lane >> 4) * 16;
  const int boff = (wn * 64 + (lane & 15)) * 64 + (lane >> 4) * 16;
  const int NT = K / 32;

  gld16((char*)Ab[0] + wbase, Ag0);
  gld16((char*)Ab[0] + 8192 + wbase, Ag1);
  gld16((char*)Bb[0] + wbase, Bg);
  gld16((char*)Ab[1] + wbase, Ag0 + 64);
  gld16((char*)Ab[1] + 8192 + wbase, Ag1 + 64);
  gld16((char*)Bb[1] + wbase, Bg + 64);

  for (int t = 0; t < NT; t++) {
    const int p = t & 1;
    if (t == NT - 1)
      asm volatile("s_waitcnt vmcnt(0)" ::: "memory");
    else
      asm volatile("s_waitcnt vmcnt(3)" ::: "memory");
    __builtin_amdgcn_s_barrier();
    s16x8 af[4], bf[4];
    const char* pa = (const char*)Ab[p] + aoff;
    const char* pb = (const char*)Bb[p] + boff;
#pragma unroll
    for (int m = 0; m < 4; m++) af[m] = *(const s16x8*)(pa + m * 1024);
#pragma unroll
    for (int n = 0; n < 4; n++) bf[n] = *(const s16x8*)(pb + n * 1024);
#pragma unroll
    for (int m = 0; m < 4; m++)
#pragma unroll
      for (int n = 0; n < 4; n++) acc[m][n] = mfma16(af[m], bf[n], acc[m][n]);
    __builtin_amdgcn_s_barrier();
    __builtin_amdgcn_sched_barrier(0);
    if (t + 2 < NT) {
      const size_t kb = (size_t)(t + 2) * 64;
      gld16((char*)Ab[p] + wbase, Ag0 + kb);
      gld16((char*)Ab[p] + 8192 + wbase, Ag1 + kb);
      gld16((char*)Bb[p] + wbase, Bg + kb);
    }
  }
#pragma unroll
  for (int m = 0; m < 4; m++)
#pragma unroll
    for (int n = 0; n < 4; n++)
#pragma unroll
      for (int j = 0; j < 4; j++) {
        const int r = bm * 256 + wm * 64 + m * 16 + (lane >> 4) * 4 + j;
        const int c = bn * 128 + wn * 64 + n * 16 + (lane & 15);
        C[(size_t)r * N + c] = acc[m][n][j] + bias[c];
      }
}

extern "C" void kernel_launch(void* const* d_in, const int* in_sizes, int n_in,
                              void* d_out, int out_size, void* d_ws,
                              size_t ws_size, hipStream_t stream) {
  (void)in_sizes; (void)n_in; (void)out_size; (void)ws_size;
  const int* tokens = (const int*)d_in[0];
  const float* embed = (const float*)d_in[1];
  const float* Wq = (const float*)d_in[2];
  const float* Wk = (const float*)d_in[3];
  const float* Wv = (const float*)d_in[4];
  const float* Wo = (const float*)d_in[5];
  const float* slot_keys = (const float*)d_in[6];
  const float* ln_g = (const float*)d_in[7];
  const float* ln_b = (const float*)d_in[8];
  const float* fg = (const float*)d_in[9];
  const float* fb = (const float*)d_in[10];
  const float* Wout = (const float*)d_in[11];
  const float* bout = (const float*)d_in[12];
  float* out = (float*)d_out;

  char* p = (char*)d_ws;
  auto alloc = [&](size_t bytes) -> char* {
    char* r = p;
    p += (bytes + 255) & ~(size_t)255;
    return r;
  };
  const size_t RD = (size_t)NROWS * DIMM;
  double* hidden64 = (double*)alloc(RD * 8);
  double* xn64 = (double*)alloc(RD * 8);
  float* q32 = (float*)alloc(RD * 4);          // aliased as xnb at end
  float* k32 = (float*)alloc(RD * 4);          // k32+v32 aliased as WoutT
  float* v32 = (float*)alloc(RD * 4);
  float* local32 = (float*)alloc(RD * 4);
  double* delta64 =
      (double*)alloc((size_t)NB * NHEADS * NCHUNK * NSLOTS * DH * 8);
  int* ri = (int*)alloc((size_t)65536 * 16 * 4);
  int* wi = (int*)alloc((size_t)65536 * 16 * 4);
  double* rw64 = (double*)alloc((size_t)65536 * 16 * 8);
  double* ww64 = (double*)alloc((size_t)65536 * 16 * 8);
  u16* sAh = (u16*)alloc(RD * 2);
  u16* sAm = (u16*)alloc(RD * 2);
  u16* sAl = (u16*)alloc(RD * 2);
  u16* kBh = (u16*)alloc(RD * 2);
  u16* kBm = (u16*)alloc(RD * 2);
  u16* kBl = (u16*)alloc(RD * 2);
  u16* WTh = (u16*)alloc((size_t)8 * DIMM * DIMM * 2);
  u16* WTm = (u16*)alloc((size_t)8 * DIMM * DIMM * 2);
  u16* WTl = (u16*)alloc((size_t)8 * DIMM * DIMM * 2);
  double* W2q = (double*)alloc((size_t)2 * DIMM * DIMM * 8);
  double* W2k = (double*)alloc((size_t)2 * DIMM * DIMM * 8);
  const size_t SKE = (size_t)2 * NHEADS * NSLOTS * DH;
  u16* sk3h = (u16*)alloc(SKE * 2);
  u16* sk3m = (u16*)alloc(SKE * 2);
  u16* sk3l = (u16*)alloc(SKE * 2);
  float* S = (float*)alloc((size_t)2 * 65536 * NSLOTS * 4);
  int* fcnts = (int*)alloc(256);
  int* flq = (int*)alloc((size_t)MAXFLAG * 4);
  int* flk = (int*)alloc((size_t)MAXFLAG * 4);

  u16* xnb = (u16*)q32;
  u16* WoutT = (u16*)k32;

  const float* Wmats[4] = {Wq, Wk, Wv, Wo};
  for (int l = 0; l < 2; l++) {
    for (int w = 0; w < 4; w++) {
      const size_t o = ((size_t)l * 4 + w) * DIMM * DIMM;
      transconv3_kernel<<<dim3(DIMM / 32, DIMM / 32), dim3(32, 8), 0, stream>>>(
          Wmats[w] + (size_t)l * DIMM * DIMM, WTh + o, WTm + o, WTl + o, DIMM,
          DIMM);
    }
    const float* skl = slot_keys + (size_t)l * NHEADS * NSLOTS * DH;
    w2_kernel<<<1024, 256, 0, stream>>>(Wq + (size_t)l * DIMM * DIMM, skl,
                                        W2q + (size_t)l * DIMM * DIMM);
    w2_kernel<<<1024, 256, 0, stream>>>(Wk + (size_t)l * DIMM * DIMM, skl,
                                        W2k + (size_t)l * DIMM * DIMM);
  }
  cvt3_32_kernel<<<SKE / 1024, 256, 0, stream>>>(slot_keys, sk3h, sk3m, sk3l);

  embed64_kernel<<<NROWS, 256, 0, stream>>>(tokens, embed, hidden64);

  const dim3 g3(DIMM / 128, NROWS / 128);
  for (int l = 0; l < 2; l++) {
    const size_t oq = ((size_t)l * 4 + 0) * DIMM * DIMM;
    const size_t ok = ((size_t)l * 4 + 1) * DIMM * DIMM;
    const size_t ov = ((size_t)l * 4 + 2) * DIMM * DIMM;
    const size_t oo = ((size_t)l * 4 + 3) * DIMM * DIMM;
    const size_t sko = (size_t)l * NHEADS * NSLOTS * DH;
    ln64_kernel<0><<<NROWS, 256, 0, stream>>>(hidden64, ln_g + l * DIMM,
                                              ln_b + l * DIMM, xn64, sAh, sAm,
                                              sAl);
    gemm3d_kernel<false, float><<<g3, 256, 0, stream>>>(
        sAh, sAm, sAl, WTh + oq, WTm + oq, WTl + oq, q32, nullptr, NROWS, DIMM,
        DIMM);
    gemm3d_kernel<false, float><<<g3, 256, 0, stream>>>(
        sAh, sAm, sAl, WTh + ok, WTm + ok, WTl + ok, k32, nullptr, NROWS, DIMM,
        DIMM);
    gemm3d_kernel<false, float><<<g3, 256, 0, stream>>>(
        sAh, sAm, sAl, WTh + ov, WTm + ov, WTl + ov, v32, nullptr, NROWS, DIMM,
        DIMM);
    cvt3_32_kernel<<<RD / 1024, 256, 0, stream>>>(q32, sAh, sAm, sAl);
    cvt3_32_kernel<<<RD / 1024, 256, 0, stream>>>(k32, kBh, kBm, kBl);
    hipMemsetAsync(fcnts, 0, 8, stream);
    score3_kernel<<<dim3(32, 32), 256, 0, stream>>>(
        sAh, sAm, sAl, kBh, kBm, kBl, sk3h + sko, sk3m + sko, sk3l + sko, S);
    select_kernel<<<dim3(16384, 2), 256, 0, stream>>>(S, ri, wi, rw64, ww64,
                                                      fcnts, flq, flk);
    fixup_kernel<<<dim3(512, 2), 256, 0, stream>>>(
        fcnts, flq, flk, xn64, W2q + (size_t)l * DIMM * DIMM,
        W2k + (size_t)l * DIMM * DIMM, ri, wi, rw64, ww64);
    delta64_kernel<<<NB * NHEADS * NCHUNK, 512, 0, stream>>>(wi, ww64, v32,
                                                             delta64);
    attn_fused<<<NB * NCHUNK * NHEADS * 8, 256, 0, stream>>>(q32, k32, v32,
                                                             local32);
    recur64_kernel<<<NB * NHEADS * 8, 256, 0, stream>>>(ri, rw64, delta64,
                                                        local32, sAh, sAm,
                                                        sAl);
    gemm3d_kernel<true, double><<<g3, 256, 0, stream>>>(
        sAh, sAm, sAl, WTh + oo, WTm + oo, WTl + oo, hidden64, hidden64, NROWS,
        DIMM, DIMM);
  }
  transconv_kernel<<<dim3(NVOCAB / 32, DIMM / 32), dim3(32, 8), 0, stream>>>(
      Wout, WoutT, DIMM, NVOCAB);
  ln64_kernel<1><<<NROWS, 256, 0, stream>>>(hidden64, fg, fb, nullptr, xnb,
                                            nullptr, nullptr);
  gemm256_kernel<<<dim3(NVOCAB / 128, NROWS / 256), 512, 0, stream>>>(
      xnb, WoutT, out, bout, NROWS, NVOCAB, DIMM);
}